// Round 10
// baseline (2067.468 us; speedup 1.0000x reference)
//
#include <hip/hip_runtime.h>
#include <hip/hip_bf16.h>

// Problem constants (match reference)
#define E_LINKS 131072
#define M_PAIRS 1048576
#define DDIM    64
#define GG      1024
#define RUNITS  256
#define TITER   8

typedef __attribute__((ext_vector_type(8))) short bf16x8;
typedef __attribute__((ext_vector_type(4))) float f32x4;
typedef __attribute__((ext_vector_type(16))) float f32x16;

__device__ inline unsigned short f2bf(float f){
  union { float f; unsigned int u; } v; v.f = f;
  unsigned int u = v.u;
  unsigned int r = (u + 0x7FFFu + ((u >> 16) & 1u)) >> 16;
  return (unsigned short)r;
}
__device__ inline float bf2f(unsigned short u){
  union { unsigned int u; float f; } v; v.u = ((unsigned int)u) << 16; return v.f;
}
__device__ inline float selu_f(float x){
  return x > 0.f ? 1.0507009873554805f * x
                 : 1.7580993408473766f * (__expf(x) - 1.f);
}
__device__ inline float sigmoid_f(float x){ return 1.f / (1.f + __expf(-x)); }
__device__ inline float tanh_f(float x){
  float xc = fminf(fmaxf(x, -15.f), 15.f);
  float e2 = __expf(2.f * xc);
  return (e2 - 1.f) / (e2 + 1.f);
}

__device__ inline bf16x8 packbf8f(float4 u0, float4 u1){
  bf16x8 r;
  r[0] = (short)f2bf(u0.x); r[1] = (short)f2bf(u0.y);
  r[2] = (short)f2bf(u0.z); r[3] = (short)f2bf(u0.w);
  r[4] = (short)f2bf(u1.x); r[5] = (short)f2bf(u1.y);
  r[6] = (short)f2bf(u1.z); r[7] = (short)f2bf(u1.w);
  return r;
}

__device__ inline f32x16 zero16(){
  f32x16 v;
  #pragma unroll
  for (int i = 0; i < 16; i++) v[i] = 0.f;
  return v;
}

// ---------------- preprocessing ----------------

__global__ void k_zero(int* __restrict__ counts){
  int i = blockIdx.x * blockDim.x + threadIdx.x;
  if (i < E_LINKS) counts[i] = 0;
}

__global__ void k_hist(const int* __restrict__ second, int* __restrict__ counts){
  int i = blockIdx.x * blockDim.x + threadIdx.x;
  if (i < M_PAIRS) atomicAdd(&counts[second[i]], 1);
}

__global__ __launch_bounds__(256) void k_scan_reduce(const int* __restrict__ counts,
    int* __restrict__ partials){
  __shared__ int s[256];
  int t = threadIdx.x;
  int i = blockIdx.x * 256 + t;
  s[t] = counts[i];
  __syncthreads();
  #pragma unroll
  for (int off = 128; off > 0; off >>= 1){
    if (t < off) s[t] += s[t + off];
    __syncthreads();
  }
  if (t == 0) partials[blockIdx.x] = s[0];
}

__global__ __launch_bounds__(512) void k_scan_part(int* __restrict__ partials){
  __shared__ int s[512];
  int t = threadIdx.x;
  int v = partials[t];
  s[t] = v;
  __syncthreads();
  for (int off = 1; off < 512; off <<= 1){
    int u = (t >= off) ? s[t - off] : 0;
    __syncthreads();
    s[t] += u;
    __syncthreads();
  }
  partials[t] = s[t] - v;
}

__global__ __launch_bounds__(256) void k_scan_apply(const int* __restrict__ counts,
    const int* __restrict__ partials, int* __restrict__ offsets,
    int* __restrict__ cursor){
  __shared__ int s[256];
  int t = threadIdx.x;
  int i = blockIdx.x * 256 + t;
  int c = counts[i];
  s[t] = c;
  __syncthreads();
  for (int off = 1; off < 256; off <<= 1){
    int u = (t >= off) ? s[t - off] : 0;
    __syncthreads();
    s[t] += u;
    __syncthreads();
  }
  int run = partials[blockIdx.x] + s[t] - c;
  offsets[i] = run;
  cursor[i] = run;
  if (i == E_LINKS - 1) offsets[E_LINKS] = run + c;
}

__global__ void k_goffs(const int* __restrict__ gid, int* __restrict__ goffs){
  int i = blockIdx.x * blockDim.x + threadIdx.x;
  if (i >= E_LINKS) return;
  int g = gid[i];
  int gp = (i == 0) ? -1 : gid[i - 1];
  for (int x = gp + 1; x <= g; x++) goffs[x] = i;
  if (i == E_LINKS - 1){
    for (int x = g + 1; x <= GG; x++) goffs[x] = E_LINKS;
  }
}

__global__ void k_scatter(const int* __restrict__ first, const int* __restrict__ second,
    int* __restrict__ cursor, int* __restrict__ srcs){
  int i = blockIdx.x * blockDim.x + threadIdx.x;
  if (i < M_PAIRS){
    int e = second[i];
    int slot = atomicAdd(&cursor[e], 1);
    srcs[slot] = first[i];
  }
}

// Build transposed bf16 weights + combined biases.
__global__ void k_prepw(const float* __restrict__ W_msg,
    const float* __restrict__ gk, const float* __restrict__ grk,
    const float* __restrict__ bi, const float* __restrict__ br,
    unsigned short* __restrict__ WzrT, unsigned short* __restrict__ WxhT,
    unsigned short* __restrict__ WhhT, unsigned short* __restrict__ WcT,
    float* __restrict__ bzr, float* __restrict__ bxh, float* __restrict__ bhh){
  int i = blockIdx.x * blockDim.x + threadIdx.x;
  if (i < 16384){
    int c = i >> 7, k = i & 127;
    float v = (k < 64) ? gk[k * 192 + c] : grk[(k - 64) * 192 + c];
    WzrT[i] = f2bf(v);
  } else if (i < 20480){
    int j = i - 16384; int c = j >> 6, k = j & 63;
    WxhT[j] = f2bf(gk[k * 192 + 128 + c]);
  } else if (i < 24576){
    int j = i - 20480; int c = j >> 6, k = j & 63;
    WhhT[j] = f2bf(grk[k * 192 + 128 + c]);
  } else if (i < 32768){
    int j = i - 24576; int c = j >> 6, k = j & 63;
    float v = (c < 64) ? W_msg[k * 64 + c] : W_msg[(64 + k) * 64 + (c - 64)];
    WcT[j] = f2bf(v);
  } else if (i < 33024){
    int j = i - 32768;
    if (j < 128) bzr[j] = bi[j] + br[j];
    else if (j < 192) bxh[j - 128] = bi[j];
    else bhh[j - 192] = br[j - 64];
  }
}

// ---------------- main loop kernels ----------------

// AB[E,128] = h[E,64] @ Wc[64,128] (+ b_msg on cols>=64); h read as f32.
__global__ __launch_bounds__(256) void k_ab0(const float* __restrict__ hf,
    const unsigned short* __restrict__ WcT, const float* __restrict__ b_msg,
    unsigned short* __restrict__ AB){
  int wave = threadIdx.x >> 6, lane = threadIdx.x & 63;
  int row0 = (blockIdx.x * 4 + wave) * 16;
  int lr = lane & 15, lg = lane >> 4;
  f32x4 acc[8];
  #pragma unroll
  for (int i = 0; i < 8; i++) acc[i] = (f32x4){0.f, 0.f, 0.f, 0.f};
  #pragma unroll
  for (int s = 0; s < 2; s++){
    int kb = s * 32 + lg * 8;
    const float* p = hf + (size_t)(row0 + lr) * 64 + kb;
    bf16x8 a = packbf8f(*(const float4*)p, *(const float4*)(p + 4));
    #pragma unroll
    for (int ct = 0; ct < 8; ct++){
      bf16x8 b = *(const bf16x8*)(WcT + (ct * 16 + lr) * 64 + kb);
      acc[ct] = __builtin_amdgcn_mfma_f32_16x16x32_bf16(a, b, acc[ct], 0, 0, 0);
    }
  }
  #pragma unroll
  for (int ct = 0; ct < 8; ct++){
    int col = ct * 16 + lr;
    float bias = (col >= 64) ? b_msg[col - 64] : 0.f;
    #pragma unroll
    for (int q = 0; q < 4; q++){
      int row = row0 + lg * 4 + q;
      AB[(size_t)row * 128 + col] = f2bf(acc[ct][q] + bias);
    }
  }
}

// agg[e][:] = sum over incoming msgs: selu(A[src] + B[e])
__global__ __launch_bounds__(256) void k_agg(const unsigned short* __restrict__ AB,
    const int* __restrict__ offsets, const int* __restrict__ srcs,
    unsigned short* __restrict__ agg){
  int wave = threadIdx.x >> 6, lane = threadIdx.x & 63;
  int e = blockIdx.x * 4 + wave;
  int g = lane >> 4, d = lane & 15;

  ushort4 bq = *(const ushort4*)(AB + (size_t)e * 128 + 64 + d * 4);
  float b0 = bf2f(bq.x), b1 = bf2f(bq.y), b2 = bf2f(bq.z), b3 = bf2f(bq.w);

  int beg = offsets[e], end = offsets[e + 1];
  float a0 = 0.f, a1 = 0.f, a2 = 0.f, a3 = 0.f;

  int i = beg + g;
  for (; i + 4 < end; i += 8){
    int s0 = srcs[i];
    int s1 = srcs[i + 4];
    ushort4 q0 = *(const ushort4*)(AB + (size_t)s0 * 128 + d * 4);
    ushort4 q1 = *(const ushort4*)(AB + (size_t)s1 * 128 + d * 4);
    a0 += selu_f(bf2f(q0.x) + b0);
    a1 += selu_f(bf2f(q0.y) + b1);
    a2 += selu_f(bf2f(q0.z) + b2);
    a3 += selu_f(bf2f(q0.w) + b3);
    a0 += selu_f(bf2f(q1.x) + b0);
    a1 += selu_f(bf2f(q1.y) + b1);
    a2 += selu_f(bf2f(q1.z) + b2);
    a3 += selu_f(bf2f(q1.w) + b3);
  }
  if (i < end){
    int s0 = srcs[i];
    ushort4 q0 = *(const ushort4*)(AB + (size_t)s0 * 128 + d * 4);
    a0 += selu_f(bf2f(q0.x) + b0);
    a1 += selu_f(bf2f(q0.y) + b1);
    a2 += selu_f(bf2f(q0.z) + b2);
    a3 += selu_f(bf2f(q0.w) + b3);
  }

  a0 += __shfl_xor(a0, 16, 64); a0 += __shfl_xor(a0, 32, 64);
  a1 += __shfl_xor(a1, 16, 64); a1 += __shfl_xor(a1, 32, 64);
  a2 += __shfl_xor(a2, 16, 64); a2 += __shfl_xor(a2, 32, 64);
  a3 += __shfl_xor(a3, 16, 64); a3 += __shfl_xor(a3, 32, 64);

  if (g == 0){
    ushort4 o;
    o.x = f2bf(a0); o.y = f2bf(a1); o.z = f2bf(a2); o.w = f2bf(a3);
    *(ushort4*)(agg + (size_t)e * 64 + d * 4) = o;
  }
}

// Fused GRU (+ optional AB), 8 waves/block (512 thr), 4 row-groups of 32 rows,
// wave-pairs split the N dimension (wave sh handles cols [32*sh, 32*sh+32)).
// 32x32x16 MFMA. Layouts:
//   A/B  row|col = lane&31, k = (lane>>5)*8 + j
//   C/D  col = lane&31, row = (reg&3) + 8*(reg>>2) + 4*(lane>>5)
// LDS per group: fp32 h tile hsh[32][68] (8.7KB), cooperatively staged by the
// wave pair; h A-fragments re-read from it (no duplicate global h reads);
// reused (union) as the bf16 hn transpose tile tsh[32][64] after holds are
// consumed (barrier-protected). agg A-fragments loaded from global (L2-hot,
// duplicated across the pair). LDS/block = 34816 -> 4 blocks/CU, 32 waves/CU.
template<bool WITH_AB>
__global__ __launch_bounds__(512, 8) void k_fused(const unsigned short* __restrict__ agg,
    const float* h_in, float* h_out,
    const unsigned short* __restrict__ WzrT, const unsigned short* __restrict__ WxhT,
    const unsigned short* __restrict__ WhhT, const unsigned short* __restrict__ WcT,
    const float* __restrict__ bzr, const float* __restrict__ bxh,
    const float* __restrict__ bhh,
    const float* __restrict__ b_msg, unsigned short* __restrict__ AB){
  __shared__ float hsh[4][32][68];   // 34816B; per-group, tail-reused as tsh
  int wave = threadIdx.x >> 6, lane = threadIdx.x & 63;
  int grp = wave >> 1, sh = wave & 1;
  int row0 = (blockIdx.x * 4 + grp) * 32;
  int lc = lane & 31, lh = lane >> 5;
  int J = sh * 32;                    // this wave's output-column offset

  // ---- cooperative stage of the fp32 h tile (wave sh loads cols [J,J+32)) ----
  {
    const float* p = h_in + (size_t)(row0 + lc) * 64 + J + lh * 16;
    float4 u0 = *(const float4*)(p);
    float4 u1 = *(const float4*)(p + 4);
    float4 u2 = *(const float4*)(p + 8);
    float4 u3 = *(const float4*)(p + 12);
    float* q = &hsh[grp][lc][J + lh * 16];
    *(float4*)(q)      = u0;
    *(float4*)(q + 4)  = u1;
    *(float4*)(q + 8)  = u2;
    *(float4*)(q + 12) = u3;
  }
  __syncthreads();

  // ---- A fragments: agg from global (dup in pair, L2-hot), h from hsh ----
  bf16x8 az[8];
  const unsigned short* arow = agg + (size_t)(row0 + lc) * 64 + lh * 8;
  #pragma unroll
  for (int s = 0; s < 4; s++) az[s] = *(const bf16x8*)(arow + s * 16);
  #pragma unroll
  for (int s = 0; s < 4; s++){
    float4 u0 = *(const float4*)(&hsh[grp][lc][s * 16 + lh * 8]);
    float4 u1 = *(const float4*)(&hsh[grp][lc][s * 16 + lh * 8 + 4]);
    az[4 + s] = packbf8f(u0, u1);
  }

  // ---- r-gate GEMM (zr col 64+J+lc) ----
  f32x16 ar = zero16();
  #pragma unroll
  for (int s = 0; s < 8; s++){
    bf16x8 b = *(const bf16x8*)(WzrT + (size_t)(64 + J + lc) * 128 + lh * 8 + s * 16);
    ar = __builtin_amdgcn_mfma_f32_32x32x16_bf16(az[s], b, ar, 0, 0, 0);
  }

  // ---- xh (A=agg) / hh (A=h) GEMMs, col J+lc ----
  float cv[16];
  {
    f32x16 axh = zero16(), ahh = zero16();
    #pragma unroll
    for (int s = 0; s < 4; s++){
      bf16x8 bx = *(const bf16x8*)(WxhT + (size_t)(J + lc) * 64 + lh * 8 + s * 16);
      axh = __builtin_amdgcn_mfma_f32_32x32x16_bf16(az[s], bx, axh, 0, 0, 0);
      bf16x8 bh = *(const bf16x8*)(WhhT + (size_t)(J + lc) * 64 + lh * 8 + s * 16);
      ahh = __builtin_amdgcn_mfma_f32_32x32x16_bf16(az[4 + s], bh, ahh, 0, 0, 0);
    }
    float brv = bzr[64 + J + lc], bx = bxh[J + lc], bh = bhh[J + lc];
    #pragma unroll
    for (int r = 0; r < 16; r++){
      float rr = sigmoid_f(ar[r] + brv);
      cv[r] = tanh_f(axh[r] + bx + rr * (ahh[r] + bh));
    }
  }

  // ---- z-gate GEMM (zr col J+lc) ----
  f32x16 azt = zero16();
  #pragma unroll
  for (int s = 0; s < 8; s++){
    bf16x8 b = *(const bf16x8*)(WzrT + (size_t)(J + lc) * 128 + lh * 8 + s * 16);
    azt = __builtin_amdgcn_mfma_f32_32x32x16_bf16(az[s], b, azt, 0, 0, 0);
  }

  // ---- fold z + holds (from hsh) -> final v ----
  {
    float bz = bzr[J + lc];
    #pragma unroll
    for (int r = 0; r < 16; r++){
      int rl = (r & 3) + 8 * (r >> 2) + 4 * lh;
      float h0 = hsh[grp][rl][J + lc];
      float z = sigmoid_f(azt[r] + bz);
      cv[r] = z * h0 + (1.f - z) * cv[r];
    }
  }

  __syncthreads();   // all hsh reads complete before tsh overwrites the space

  // ---- write h_out + stash hn (swizzled bf16) into tsh (= hsh space) ----
  unsigned short* tsh = (unsigned short*)&hsh[grp][0][0];
  {
    int j = J + lc;
    #pragma unroll
    for (int r = 0; r < 16; r++){
      int rl = (r & 3) + 8 * (r >> 2) + 4 * lh;
      h_out[(size_t)(row0 + rl) * 64 + j] = cv[r];
      if (WITH_AB)
        tsh[rl * 64 + (((j >> 3) ^ (rl & 7)) << 3) + (j & 7)] = f2bf(cv[r]);
    }
  }

  if (WITH_AB){
    __syncthreads();   // full hn tile visible to both waves of the pair
    // AB GEMM: M=32, K=64; this wave computes cols [64*sh, 64*sh+64)
    f32x16 acc[2];
    acc[0] = zero16(); acc[1] = zero16();
    #pragma unroll
    for (int s = 0; s < 4; s++){
      int blk = ((s * 2 + lh) ^ (lc & 7)) << 3;
      bf16x8 a = *(const bf16x8*)(&tsh[lc * 64 + blk]);
      #pragma unroll
      for (int ct = 0; ct < 2; ct++){
        int col = sh * 64 + ct * 32 + lc;
        bf16x8 b = *(const bf16x8*)(WcT + (size_t)col * 64 + lh * 8 + s * 16);
        acc[ct] = __builtin_amdgcn_mfma_f32_32x32x16_bf16(a, b, acc[ct], 0, 0, 0);
      }
    }
    #pragma unroll
    for (int ct = 0; ct < 2; ct++){
      int col = sh * 64 + ct * 32 + lc;
      float bias = (col >= 64) ? b_msg[col - 64] : 0.f;
      #pragma unroll
      for (int r = 0; r < 16; r++){
        int rl = (r & 3) + 8 * (r >> 2) + 4 * lh;
        AB[(size_t)(row0 + rl) * 128 + col] = f2bf(acc[ct][r] + bias);
      }
    }
  }
}

// ---------------- readout ----------------

__global__ __launch_bounds__(256) void k_seg(const float* __restrict__ hf,
    const int* __restrict__ goff, float* __restrict__ gsum){
  int wave = threadIdx.x >> 6, lane = threadIdx.x & 63;
  int g = blockIdx.x * 4 + wave;
  int beg = goff[g], end = goff[g + 1];
  float acc = 0.f;
  for (int e = beg; e < end; e++) acc += hf[(size_t)e * 64 + lane];
  gsum[(size_t)g * 64 + lane] = acc;
}

__global__ __launch_bounds__(256) void k_mlp(const float* __restrict__ gsum,
    const float* __restrict__ W1, const float* __restrict__ b1,
    const float* __restrict__ W2, const float* __restrict__ b2,
    const float* __restrict__ W3, const float* __restrict__ b3,
    float* __restrict__ out){
  __shared__ float sg[64];
  __shared__ float sr1[256];
  __shared__ float sr2[256];
  __shared__ float wsum[4];
  int g = blockIdx.x, t = threadIdx.x;
  if (t < 64) sg[t] = gsum[(size_t)g * 64 + t];
  __syncthreads();
  float a = b1[t];
  #pragma unroll
  for (int k = 0; k < 64; k++) a += sg[k] * W1[k * 256 + t];
  sr1[t] = selu_f(a);
  __syncthreads();
  float b = b2[t];
  for (int k = 0; k < 256; k++) b += sr1[k] * W2[k * 256 + t];
  sr2[t] = selu_f(b);
  __syncthreads();
  float v = sr2[t] * W3[t];
  for (int off = 32; off > 0; off >>= 1) v += __shfl_down(v, off, 64);
  if ((t & 63) == 0) wsum[t >> 6] = v;
  __syncthreads();
  if (t == 0) out[g] = wsum[0] + wsum[1] + wsum[2] + wsum[3] + b3[0];
}

// ---------------- host ----------------

static inline size_t alignup(size_t x){ return (x + 255) & ~(size_t)255; }

extern "C" void kernel_launch(void* const* d_in, const int* in_sizes, int n_in,
                              void* d_out, int out_size, void* d_ws, size_t ws_size,
                              hipStream_t stream) {
  const float* states_action = (const float*)d_in[0];
  const int*   graph_ids     = (const int*)d_in[1];
  const int*   first         = (const int*)d_in[2];
  const int*   second        = (const int*)d_in[3];
  const float* W_msg         = (const float*)d_in[5];
  const float* b_msg         = (const float*)d_in[6];
  const float* gk            = (const float*)d_in[7];
  const float* grk           = (const float*)d_in[8];
  const float* bi            = (const float*)d_in[9];
  const float* br            = (const float*)d_in[10];
  const float* W1            = (const float*)d_in[11];
  const float* b1            = (const float*)d_in[12];
  const float* W2            = (const float*)d_in[13];
  const float* b2            = (const float*)d_in[14];
  const float* W3            = (const float*)d_in[15];
  const float* b3            = (const float*)d_in[16];
  float* out = (float*)d_out;

  char* ws = (char*)d_ws;
  size_t off = 0;
  float*          h_f32  = (float*)(ws + off);          off += alignup((size_t)E_LINKS * 64 * 4);
  unsigned short* aggb   = (unsigned short*)(ws + off); off += alignup((size_t)E_LINKS * 64 * 2);
  unsigned short* AB     = (unsigned short*)(ws + off); off += alignup((size_t)E_LINKS * 128 * 2);
  unsigned short* WzrT   = (unsigned short*)(ws + off); off += alignup(128 * 128 * 2);
  unsigned short* WxhT   = (unsigned short*)(ws + off); off += alignup(64 * 64 * 2);
  unsigned short* WhhT   = (unsigned short*)(ws + off); off += alignup(64 * 64 * 2);
  unsigned short* WcT    = (unsigned short*)(ws + off); off += alignup(128 * 64 * 2);
  float*          bzr    = (float*)(ws + off);          off += alignup(128 * 4);
  float*          bxhv   = (float*)(ws + off);          off += alignup(64 * 4);
  float*          bhhv   = (float*)(ws + off);          off += alignup(64 * 4);
  int*            counts = (int*)(ws + off);            off += alignup((size_t)E_LINKS * 4);
  int*            offs   = (int*)(ws + off);            off += alignup(((size_t)E_LINKS + 1) * 4);
  int*            cursor = (int*)(ws + off);            off += alignup((size_t)E_LINKS * 4);
  int*            srcs   = (int*)(ws + off);            off += alignup((size_t)M_PAIRS * 4);
  int*            parts  = (int*)(ws + off);            off += alignup(512 * 4);
  int*            goffs  = (int*)(ws + off);            off += alignup(((size_t)GG + 1) * 4);
  float*          gsum   = (float*)(ws + off);          off += alignup((size_t)GG * 64 * 4);

  dim3 b256(256);

  // CSR preprocessing
  k_zero<<<dim3(E_LINKS / 256), b256, 0, stream>>>(counts);
  k_hist<<<dim3(M_PAIRS / 256), b256, 0, stream>>>(second, counts);
  k_scan_reduce<<<dim3(512), b256, 0, stream>>>(counts, parts);
  k_scan_part<<<dim3(1), dim3(512), 0, stream>>>(parts);
  k_scan_apply<<<dim3(512), b256, 0, stream>>>(counts, parts, offs, cursor);
  k_goffs<<<dim3(E_LINKS / 256), b256, 0, stream>>>(graph_ids, goffs);
  k_scatter<<<dim3(M_PAIRS / 256), b256, 0, stream>>>(first, second, cursor, srcs);

  // weights (33024 elements total -> 129 blocks)
  k_prepw<<<dim3(129), b256, 0, stream>>>(W_msg, gk, grk, bi, br,
      WzrT, WxhT, WhhT, WcT, bzr, bxhv, bhhv);

  // t=0 message precompute from initial h (= states_action)
  k_ab0<<<dim3(E_LINKS / 64), b256, 0, stream>>>(states_action, WcT, b_msg, AB);

  // message passing: split kernels, single AB buffer (L2-friendly)
  for (int t = 0; t < TITER; t++){
    k_agg<<<dim3(E_LINKS / 4), b256, 0, stream>>>(AB, offs, srcs, aggb);
    const float* h_in = (t == 0) ? states_action : h_f32;
    if (t < TITER - 1)
      k_fused<true><<<dim3(E_LINKS / 128), dim3(512), 0, stream>>>(aggb, h_in, h_f32,
          WzrT, WxhT, WhhT, WcT, bzr, bxhv, bhhv, b_msg, AB);
    else
      k_fused<false><<<dim3(E_LINKS / 128), dim3(512), 0, stream>>>(aggb, h_in, h_f32,
          WzrT, WxhT, WhhT, WcT, bzr, bxhv, bhhv, b_msg, AB);
  }

  // readout
  k_seg<<<dim3(GG / 4), b256, 0, stream>>>(h_f32, goffs, gsum);
  k_mlp<<<dim3(GG), b256, 0, stream>>>(gsum, W1, b1, W2, b2, W3, b3, out);
}

// Round 11
// 1020.191 us; speedup vs baseline: 2.0265x; 2.0265x over previous
//
#include <hip/hip_runtime.h>
#include <hip/hip_bf16.h>

// Problem constants (match reference)
#define E_LINKS 131072
#define M_PAIRS 1048576
#define DDIM    64
#define GG      1024
#define RUNITS  256
#define TITER   8

typedef __attribute__((ext_vector_type(8))) short bf16x8;
typedef __attribute__((ext_vector_type(4))) float f32x4;
typedef __attribute__((ext_vector_type(16))) float f32x16;

__device__ inline unsigned short f2bf(float f){
  union { float f; unsigned int u; } v; v.f = f;
  unsigned int u = v.u;
  unsigned int r = (u + 0x7FFFu + ((u >> 16) & 1u)) >> 16;
  return (unsigned short)r;
}
__device__ inline float bf2f(unsigned short u){
  union { unsigned int u; float f; } v; v.u = ((unsigned int)u) << 16; return v.f;
}
__device__ inline float selu_f(float x){
  return x > 0.f ? 1.0507009873554805f * x
                 : 1.7580993408473766f * (__expf(x) - 1.f);
}
__device__ inline float sigmoid_f(float x){ return 1.f / (1.f + __expf(-x)); }
__device__ inline float tanh_f(float x){
  float xc = fminf(fmaxf(x, -15.f), 15.f);
  float e2 = __expf(2.f * xc);
  return (e2 - 1.f) / (e2 + 1.f);
}

__device__ inline bf16x8 packbf8f(float4 u0, float4 u1){
  bf16x8 r;
  r[0] = (short)f2bf(u0.x); r[1] = (short)f2bf(u0.y);
  r[2] = (short)f2bf(u0.z); r[3] = (short)f2bf(u0.w);
  r[4] = (short)f2bf(u1.x); r[5] = (short)f2bf(u1.y);
  r[6] = (short)f2bf(u1.z); r[7] = (short)f2bf(u1.w);
  return r;
}

__device__ inline f32x16 zero16(){
  f32x16 v;
  #pragma unroll
  for (int i = 0; i < 16; i++) v[i] = 0.f;
  return v;
}

// ---------------- preprocessing ----------------

__global__ void k_zero(int* __restrict__ counts){
  int i = blockIdx.x * blockDim.x + threadIdx.x;
  if (i < E_LINKS) counts[i] = 0;
}

__global__ void k_hist(const int* __restrict__ second, int* __restrict__ counts){
  int i = blockIdx.x * blockDim.x + threadIdx.x;
  if (i < M_PAIRS) atomicAdd(&counts[second[i]], 1);
}

__global__ __launch_bounds__(256) void k_scan_reduce(const int* __restrict__ counts,
    int* __restrict__ partials){
  __shared__ int s[256];
  int t = threadIdx.x;
  int i = blockIdx.x * 256 + t;
  s[t] = counts[i];
  __syncthreads();
  #pragma unroll
  for (int off = 128; off > 0; off >>= 1){
    if (t < off) s[t] += s[t + off];
    __syncthreads();
  }
  if (t == 0) partials[blockIdx.x] = s[0];
}

__global__ __launch_bounds__(512) void k_scan_part(int* __restrict__ partials){
  __shared__ int s[512];
  int t = threadIdx.x;
  int v = partials[t];
  s[t] = v;
  __syncthreads();
  for (int off = 1; off < 512; off <<= 1){
    int u = (t >= off) ? s[t - off] : 0;
    __syncthreads();
    s[t] += u;
    __syncthreads();
  }
  partials[t] = s[t] - v;
}

__global__ __launch_bounds__(256) void k_scan_apply(const int* __restrict__ counts,
    const int* __restrict__ partials, int* __restrict__ offsets,
    int* __restrict__ cursor){
  __shared__ int s[256];
  int t = threadIdx.x;
  int i = blockIdx.x * 256 + t;
  int c = counts[i];
  s[t] = c;
  __syncthreads();
  for (int off = 1; off < 256; off <<= 1){
    int u = (t >= off) ? s[t - off] : 0;
    __syncthreads();
    s[t] += u;
    __syncthreads();
  }
  int run = partials[blockIdx.x] + s[t] - c;
  offsets[i] = run;
  cursor[i] = run;
  if (i == E_LINKS - 1) offsets[E_LINKS] = run + c;
}

__global__ void k_goffs(const int* __restrict__ gid, int* __restrict__ goffs){
  int i = blockIdx.x * blockDim.x + threadIdx.x;
  if (i >= E_LINKS) return;
  int g = gid[i];
  int gp = (i == 0) ? -1 : gid[i - 1];
  for (int x = gp + 1; x <= g; x++) goffs[x] = i;
  if (i == E_LINKS - 1){
    for (int x = g + 1; x <= GG; x++) goffs[x] = E_LINKS;
  }
}

__global__ void k_scatter(const int* __restrict__ first, const int* __restrict__ second,
    int* __restrict__ cursor, int* __restrict__ srcs){
  int i = blockIdx.x * blockDim.x + threadIdx.x;
  if (i < M_PAIRS){
    int e = second[i];
    int slot = atomicAdd(&cursor[e], 1);
    srcs[slot] = first[i];
  }
}

// Build transposed bf16 weights + combined biases.
__global__ void k_prepw(const float* __restrict__ W_msg,
    const float* __restrict__ gk, const float* __restrict__ grk,
    const float* __restrict__ bi, const float* __restrict__ br,
    unsigned short* __restrict__ WzrT, unsigned short* __restrict__ WxhT,
    unsigned short* __restrict__ WhhT, unsigned short* __restrict__ WcT,
    float* __restrict__ bzr, float* __restrict__ bxh, float* __restrict__ bhh){
  int i = blockIdx.x * blockDim.x + threadIdx.x;
  if (i < 16384){
    int c = i >> 7, k = i & 127;
    float v = (k < 64) ? gk[k * 192 + c] : grk[(k - 64) * 192 + c];
    WzrT[i] = f2bf(v);
  } else if (i < 20480){
    int j = i - 16384; int c = j >> 6, k = j & 63;
    WxhT[j] = f2bf(gk[k * 192 + 128 + c]);
  } else if (i < 24576){
    int j = i - 20480; int c = j >> 6, k = j & 63;
    WhhT[j] = f2bf(grk[k * 192 + 128 + c]);
  } else if (i < 32768){
    int j = i - 24576; int c = j >> 6, k = j & 63;
    float v = (c < 64) ? W_msg[k * 64 + c] : W_msg[(64 + k) * 64 + (c - 64)];
    WcT[j] = f2bf(v);
  } else if (i < 33024){
    int j = i - 32768;
    if (j < 128) bzr[j] = bi[j] + br[j];
    else if (j < 192) bxh[j - 128] = bi[j];
    else bhh[j - 192] = br[j - 64];
  }
}

// ---------------- main loop kernels ----------------

// AB[E,128] = h[E,64] @ Wc[64,128] (+ b_msg on cols>=64); h read as f32.
__global__ __launch_bounds__(256) void k_ab0(const float* __restrict__ hf,
    const unsigned short* __restrict__ WcT, const float* __restrict__ b_msg,
    unsigned short* __restrict__ AB){
  int wave = threadIdx.x >> 6, lane = threadIdx.x & 63;
  int row0 = (blockIdx.x * 4 + wave) * 16;
  int lr = lane & 15, lg = lane >> 4;
  f32x4 acc[8];
  #pragma unroll
  for (int i = 0; i < 8; i++) acc[i] = (f32x4){0.f, 0.f, 0.f, 0.f};
  #pragma unroll
  for (int s = 0; s < 2; s++){
    int kb = s * 32 + lg * 8;
    const float* p = hf + (size_t)(row0 + lr) * 64 + kb;
    bf16x8 a = packbf8f(*(const float4*)p, *(const float4*)(p + 4));
    #pragma unroll
    for (int ct = 0; ct < 8; ct++){
      bf16x8 b = *(const bf16x8*)(WcT + (ct * 16 + lr) * 64 + kb);
      acc[ct] = __builtin_amdgcn_mfma_f32_16x16x32_bf16(a, b, acc[ct], 0, 0, 0);
    }
  }
  #pragma unroll
  for (int ct = 0; ct < 8; ct++){
    int col = ct * 16 + lr;
    float bias = (col >= 64) ? b_msg[col - 64] : 0.f;
    #pragma unroll
    for (int q = 0; q < 4; q++){
      int row = row0 + lg * 4 + q;
      AB[(size_t)row * 128 + col] = f2bf(acc[ct][q] + bias);
    }
  }
}

// agg[e][:] = sum over incoming msgs: selu(A[src] + B[e])
// One wave per edge; 8 lane-groups of 8 each gather one 128B source row per
// iteration (bf16x8 = 16B/lane), 2x unrolled -> 16 rows in flight per wave.
__global__ __launch_bounds__(256) void k_agg(const unsigned short* __restrict__ AB,
    const int* __restrict__ offsets, const int* __restrict__ srcs,
    unsigned short* __restrict__ agg){
  int wave = threadIdx.x >> 6, lane = threadIdx.x & 63;
  int e = blockIdx.x * 4 + wave;
  int g = lane >> 3, d = lane & 7;   // 8 groups x 8 lanes

  bf16x8 bq = *(const bf16x8*)(AB + (size_t)e * 128 + 64 + d * 8);
  float bv[8];
  #pragma unroll
  for (int j = 0; j < 8; j++) bv[j] = bf2f((unsigned short)bq[j]);

  int beg = offsets[e], end = offsets[e + 1];
  float acc[8];
  #pragma unroll
  for (int j = 0; j < 8; j++) acc[j] = 0.f;

  int i = beg + g;
  // 2x unrolled: 16 source rows in flight per wave
  for (; i + 8 < end; i += 16){
    int s0 = srcs[i];
    int s1 = srcs[i + 8];
    bf16x8 q0 = *(const bf16x8*)(AB + (size_t)s0 * 128 + d * 8);
    bf16x8 q1 = *(const bf16x8*)(AB + (size_t)s1 * 128 + d * 8);
    #pragma unroll
    for (int j = 0; j < 8; j++) acc[j] += selu_f(bf2f((unsigned short)q0[j]) + bv[j]);
    #pragma unroll
    for (int j = 0; j < 8; j++) acc[j] += selu_f(bf2f((unsigned short)q1[j]) + bv[j]);
  }
  if (i < end){
    int s0 = srcs[i];
    bf16x8 q0 = *(const bf16x8*)(AB + (size_t)s0 * 128 + d * 8);
    #pragma unroll
    for (int j = 0; j < 8; j++) acc[j] += selu_f(bf2f((unsigned short)q0[j]) + bv[j]);
  }

  // reduce across the 8 lane groups (same dims, different sources)
  #pragma unroll
  for (int j = 0; j < 8; j++){
    acc[j] += __shfl_xor(acc[j], 8, 64);
    acc[j] += __shfl_xor(acc[j], 16, 64);
    acc[j] += __shfl_xor(acc[j], 32, 64);
  }

  if (g == 0){
    bf16x8 o;
    #pragma unroll
    for (int j = 0; j < 8; j++) o[j] = (short)f2bf(acc[j]);
    *(bf16x8*)(agg + (size_t)e * 64 + d * 8) = o;
  }
}

// Fused GRU (+ optional AB), 32 rows/wave via 32x32x16 MFMA.
// Layouts: A/B  row|col = lane&31, k = (lane>>5)*8 + j
//          C/D  col = lane&31, row = (reg&3) + 8*(reg>>2) + 4*(lane>>5)
// LDS: per-wave fp32 hold tile hsh[32][68] (8.7KB), REUSED (union) as the
// bf16 transpose tile tsh[32][64] after holds are consumed. Phase split:
//   GEMMs -> read all holds (compute v into regs) -> __syncthreads -> write
//   h_out + tsh -> AB GEMM. The barrier makes the aliasing safe.
// LDS/block = 34816 -> 4 blocks/CU; VGPR ~64 -> 16 waves/CU.
template<bool WITH_AB>
__global__ __launch_bounds__(256, 4) void k_fused(const unsigned short* __restrict__ agg,
    const float* h_in, float* h_out,
    const unsigned short* __restrict__ WzrT, const unsigned short* __restrict__ WxhT,
    const unsigned short* __restrict__ WhhT, const unsigned short* __restrict__ WcT,
    const float* __restrict__ bzr, const float* __restrict__ bxh,
    const float* __restrict__ bhh,
    const float* __restrict__ b_msg, unsigned short* __restrict__ AB){
  __shared__ float hsh[4][32][68];   // 34816B; tail-reused as tsh
  int wave = threadIdx.x >> 6, lane = threadIdx.x & 63;
  int row0 = (blockIdx.x * 4 + wave) * 32;
  int lc = lane & 31, lh = lane >> 5;
  unsigned short* tsh = (unsigned short*)&hsh[wave][0][0]; // [32][64] bf16, swizzled

  // ---- A fragments over combined K=128 ([agg | h]) + fp32 hold stash ----
  bf16x8 az[8];
  const unsigned short* arow = agg + (size_t)(row0 + lc) * 64 + lh * 8;
  #pragma unroll
  for (int s = 0; s < 4; s++) az[s] = *(const bf16x8*)(arow + s * 16);
  const float* hrow = h_in + (size_t)(row0 + lc) * 64 + lh * 8;
  #pragma unroll
  for (int s = 0; s < 4; s++){
    float4 u0 = *(const float4*)(hrow + s * 16);
    float4 u1 = *(const float4*)(hrow + s * 16 + 4);
    az[4 + s] = packbf8f(u0, u1);
    *(float4*)(&hsh[wave][lc][s * 16 + lh * 8]) = u0;
    *(float4*)(&hsh[wave][lc][s * 16 + lh * 8 + 4]) = u1;
  }

  // ---- r-gate GEMM (zr tiles 2,3 -> cols 64..127) ----
  f32x16 ar0 = zero16(), ar1 = zero16();
  #pragma unroll
  for (int s = 0; s < 8; s++){
    const unsigned short* wk = WzrT + lh * 8 + s * 16;
    bf16x8 b2 = *(const bf16x8*)(wk + (size_t)(64 + lc) * 128);
    bf16x8 b3 = *(const bf16x8*)(wk + (size_t)(96 + lc) * 128);
    ar0 = __builtin_amdgcn_mfma_f32_32x32x16_bf16(az[s], b2, ar0, 0, 0, 0);
    ar1 = __builtin_amdgcn_mfma_f32_32x32x16_bf16(az[s], b3, ar1, 0, 0, 0);
  }

  float cv[2][16];

  // ---- cols 0..31: xh0 (A=agg), hh0 (A=h) -> cv[0] ----
  {
    f32x16 axh = zero16(), ahh = zero16();
    #pragma unroll
    for (int s = 0; s < 4; s++){
      const unsigned short* wx = WxhT + lh * 8 + s * 16;
      axh = __builtin_amdgcn_mfma_f32_32x32x16_bf16(az[s],
          *(const bf16x8*)(wx + (size_t)lc * 64), axh, 0, 0, 0);
      const unsigned short* wh = WhhT + lh * 8 + s * 16;
      ahh = __builtin_amdgcn_mfma_f32_32x32x16_bf16(az[4 + s],
          *(const bf16x8*)(wh + (size_t)lc * 64), ahh, 0, 0, 0);
    }
    float brv = bzr[64 + lc], bx = bxh[lc], bh = bhh[lc];
    #pragma unroll
    for (int r = 0; r < 16; r++){
      float rr = sigmoid_f(ar0[r] + brv);
      cv[0][r] = tanh_f(axh[r] + bx + rr * (ahh[r] + bh));
    }
  }

  // ---- cols 32..63: xh1, hh1 -> cv[1] ----
  {
    f32x16 axh = zero16(), ahh = zero16();
    #pragma unroll
    for (int s = 0; s < 4; s++){
      const unsigned short* wx = WxhT + lh * 8 + s * 16;
      axh = __builtin_amdgcn_mfma_f32_32x32x16_bf16(az[s],
          *(const bf16x8*)(wx + (size_t)(32 + lc) * 64), axh, 0, 0, 0);
      const unsigned short* wh = WhhT + lh * 8 + s * 16;
      ahh = __builtin_amdgcn_mfma_f32_32x32x16_bf16(az[4 + s],
          *(const bf16x8*)(wh + (size_t)(32 + lc) * 64), ahh, 0, 0, 0);
    }
    float brv = bzr[64 + 32 + lc], bx = bxh[32 + lc], bh = bhh[32 + lc];
    #pragma unroll
    for (int r = 0; r < 16; r++){
      float rr = sigmoid_f(ar1[r] + brv);
      cv[1][r] = tanh_f(axh[r] + bx + rr * (ahh[r] + bh));
    }
  }

  // ---- z-gate GEMM (zr tiles 0,1 -> cols 0..63) ----
  f32x16 azt0 = zero16(), azt1 = zero16();
  #pragma unroll
  for (int s = 0; s < 8; s++){
    const unsigned short* wk = WzrT + lh * 8 + s * 16;
    bf16x8 b0 = *(const bf16x8*)(wk + (size_t)lc * 128);
    bf16x8 b1 = *(const bf16x8*)(wk + (size_t)(32 + lc) * 128);
    azt0 = __builtin_amdgcn_mfma_f32_32x32x16_bf16(az[s], b0, azt0, 0, 0, 0);
    azt1 = __builtin_amdgcn_mfma_f32_32x32x16_bf16(az[s], b1, azt1, 0, 0, 0);
  }

  // ---- phase 1: read holds from hsh, fold z -> final v (into cv) ----
  {
    float bz0 = bzr[lc], bz1 = bzr[32 + lc];
    #pragma unroll
    for (int r = 0; r < 16; r++){
      int rl = (r & 3) + 8 * (r >> 2) + 4 * lh;
      float h0 = hsh[wave][rl][lc];
      float h1 = hsh[wave][rl][32 + lc];
      float z0 = sigmoid_f(azt0[r] + bz0);
      float z1 = sigmoid_f(azt1[r] + bz1);
      cv[0][r] = z0 * h0 + (1.f - z0) * cv[0][r];
      cv[1][r] = z1 * h1 + (1.f - z1) * cv[1][r];
    }
  }

  __syncthreads();   // all hsh reads complete before tsh overwrites the space

  // ---- phase 2: write h_out (global) + tsh (LDS, swizzled) ----
  {
    int j0 = lc, j1 = 32 + lc;
    #pragma unroll
    for (int r = 0; r < 16; r++){
      int rl = (r & 3) + 8 * (r >> 2) + 4 * lh;
      size_t base = (size_t)(row0 + rl) * 64;
      h_out[base + j0] = cv[0][r];
      h_out[base + j1] = cv[1][r];
      if (WITH_AB){
        tsh[rl * 64 + (((j0 >> 3) ^ (rl & 7)) << 3) + (j0 & 7)] = f2bf(cv[0][r]);
        tsh[rl * 64 + (((j1 >> 3) ^ (rl & 7)) << 3) + (j1 & 7)] = f2bf(cv[1][r]);
      }
    }
  }

  if (WITH_AB){
    // AB GEMM: M=32, N=128, K=64; A = hn from swizzled tsh
    f32x16 acc[4];
    #pragma unroll
    for (int i = 0; i < 4; i++) acc[i] = zero16();
    #pragma unroll
    for (int s = 0; s < 4; s++){
      int blk = ((s * 2 + lh) ^ (lc & 7)) << 3;
      bf16x8 a = *(const bf16x8*)(&tsh[lc * 64 + blk]);
      const unsigned short* wc = WcT + lh * 8 + s * 16;
      #pragma unroll
      for (int ct = 0; ct < 4; ct++){
        bf16x8 b = *(const bf16x8*)(wc + (size_t)(ct * 32 + lc) * 64);
        acc[ct] = __builtin_amdgcn_mfma_f32_32x32x16_bf16(a, b, acc[ct], 0, 0, 0);
      }
    }
    #pragma unroll
    for (int ct = 0; ct < 4; ct++){
      int col = ct * 32 + lc;
      float bias = (col >= 64) ? b_msg[col - 64] : 0.f;
      #pragma unroll
      for (int r = 0; r < 16; r++){
        int rl = (r & 3) + 8 * (r >> 2) + 4 * lh;
        AB[(size_t)(row0 + rl) * 128 + col] = f2bf(acc[ct][r] + bias);
      }
    }
  }
}

// ---------------- readout ----------------

__global__ __launch_bounds__(256) void k_seg(const float* __restrict__ hf,
    const int* __restrict__ goff, float* __restrict__ gsum){
  int wave = threadIdx.x >> 6, lane = threadIdx.x & 63;
  int g = blockIdx.x * 4 + wave;
  int beg = goff[g], end = goff[g + 1];
  float acc = 0.f;
  for (int e = beg; e < end; e++) acc += hf[(size_t)e * 64 + lane];
  gsum[(size_t)g * 64 + lane] = acc;
}

__global__ __launch_bounds__(256) void k_mlp(const float* __restrict__ gsum,
    const float* __restrict__ W1, const float* __restrict__ b1,
    const float* __restrict__ W2, const float* __restrict__ b2,
    const float* __restrict__ W3, const float* __restrict__ b3,
    float* __restrict__ out){
  __shared__ float sg[64];
  __shared__ float sr1[256];
  __shared__ float sr2[256];
  __shared__ float wsum[4];
  int g = blockIdx.x, t = threadIdx.x;
  if (t < 64) sg[t] = gsum[(size_t)g * 64 + t];
  __syncthreads();
  float a = b1[t];
  #pragma unroll
  for (int k = 0; k < 64; k++) a += sg[k] * W1[k * 256 + t];
  sr1[t] = selu_f(a);
  __syncthreads();
  float b = b2[t];
  for (int k = 0; k < 256; k++) b += sr1[k] * W2[k * 256 + t];
  sr2[t] = selu_f(b);
  __syncthreads();
  float v = sr2[t] * W3[t];
  for (int off = 32; off > 0; off >>= 1) v += __shfl_down(v, off, 64);
  if ((t & 63) == 0) wsum[t >> 6] = v;
  __syncthreads();
  if (t == 0) out[g] = wsum[0] + wsum[1] + wsum[2] + wsum[3] + b3[0];
}

// ---------------- host ----------------

static inline size_t alignup(size_t x){ return (x + 255) & ~(size_t)255; }

extern "C" void kernel_launch(void* const* d_in, const int* in_sizes, int n_in,
                              void* d_out, int out_size, void* d_ws, size_t ws_size,
                              hipStream_t stream) {
  const float* states_action = (const float*)d_in[0];
  const int*   graph_ids     = (const int*)d_in[1];
  const int*   first         = (const int*)d_in[2];
  const int*   second        = (const int*)d_in[3];
  const float* W_msg         = (const float*)d_in[5];
  const float* b_msg         = (const float*)d_in[6];
  const float* gk            = (const float*)d_in[7];
  const float* grk           = (const float*)d_in[8];
  const float* bi            = (const float*)d_in[9];
  const float* br            = (const float*)d_in[10];
  const float* W1            = (const float*)d_in[11];
  const float* b1            = (const float*)d_in[12];
  const float* W2            = (const float*)d_in[13];
  const float* b2            = (const float*)d_in[14];
  const float* W3            = (const float*)d_in[15];
  const float* b3            = (const float*)d_in[16];
  float* out = (float*)d_out;

  char* ws = (char*)d_ws;
  size_t off = 0;
  float*          h_f32  = (float*)(ws + off);          off += alignup((size_t)E_LINKS * 64 * 4);
  unsigned short* aggb   = (unsigned short*)(ws + off); off += alignup((size_t)E_LINKS * 64 * 2);
  unsigned short* AB     = (unsigned short*)(ws + off); off += alignup((size_t)E_LINKS * 128 * 2);
  unsigned short* WzrT   = (unsigned short*)(ws + off); off += alignup(128 * 128 * 2);
  unsigned short* WxhT   = (unsigned short*)(ws + off); off += alignup(64 * 64 * 2);
  unsigned short* WhhT   = (unsigned short*)(ws + off); off += alignup(64 * 64 * 2);
  unsigned short* WcT    = (unsigned short*)(ws + off); off += alignup(128 * 64 * 2);
  float*          bzr    = (float*)(ws + off);          off += alignup(128 * 4);
  float*          bxhv   = (float*)(ws + off);          off += alignup(64 * 4);
  float*          bhhv   = (float*)(ws + off);          off += alignup(64 * 4);
  int*            counts = (int*)(ws + off);            off += alignup((size_t)E_LINKS * 4);
  int*            offs   = (int*)(ws + off);            off += alignup(((size_t)E_LINKS + 1) * 4);
  int*            cursor = (int*)(ws + off);            off += alignup((size_t)E_LINKS * 4);
  int*            srcs   = (int*)(ws + off);            off += alignup((size_t)M_PAIRS * 4);
  int*            parts  = (int*)(ws + off);            off += alignup(512 * 4);
  int*            goffs  = (int*)(ws + off);            off += alignup(((size_t)GG + 1) * 4);
  float*          gsum   = (float*)(ws + off);          off += alignup((size_t)GG * 64 * 4);

  dim3 b256(256);

  // CSR preprocessing
  k_zero<<<dim3(E_LINKS / 256), b256, 0, stream>>>(counts);
  k_hist<<<dim3(M_PAIRS / 256), b256, 0, stream>>>(second, counts);
  k_scan_reduce<<<dim3(512), b256, 0, stream>>>(counts, parts);
  k_scan_part<<<dim3(1), dim3(512), 0, stream>>>(parts);
  k_scan_apply<<<dim3(512), b256, 0, stream>>>(counts, parts, offs, cursor);
  k_goffs<<<dim3(E_LINKS / 256), b256, 0, stream>>>(graph_ids, goffs);
  k_scatter<<<dim3(M_PAIRS / 256), b256, 0, stream>>>(first, second, cursor, srcs);

  // weights (33024 elements total -> 129 blocks)
  k_prepw<<<dim3(129), b256, 0, stream>>>(W_msg, gk, grk, bi, br,
      WzrT, WxhT, WhhT, WcT, bzr, bxhv, bhhv);

  // t=0 message precompute from initial h (= states_action)
  k_ab0<<<dim3(E_LINKS / 64), b256, 0, stream>>>(states_action, WcT, b_msg, AB);

  // message passing: split kernels, single AB buffer (L2-friendly)
  for (int t = 0; t < TITER; t++){
    k_agg<<<dim3(E_LINKS / 4), b256, 0, stream>>>(AB, offs, srcs, aggb);
    const float* h_in = (t == 0) ? states_action : h_f32;
    if (t < TITER - 1)
      k_fused<true><<<dim3(E_LINKS / 128), b256, 0, stream>>>(aggb, h_in, h_f32,
          WzrT, WxhT, WhhT, WcT, bzr, bxhv, bhhv, b_msg, AB);
    else
      k_fused<false><<<dim3(E_LINKS / 128), b256, 0, stream>>>(aggb, h_in, h_f32,
          WzrT, WxhT, WhhT, WcT, bzr, bxhv, bhhv, b_msg, AB);
  }

  // readout
  k_seg<<<dim3(GG / 4), b256, 0, stream>>>(h_f32, goffs, gsum);
  k_mlp<<<dim3(GG), b256, 0, stream>>>(gsum, W1, b1, W2, b2, W3, b3, out);
}

// Round 12
// 958.786 us; speedup vs baseline: 2.1563x; 1.0640x over previous
//
#include <hip/hip_runtime.h>
#include <hip/hip_bf16.h>

// Problem constants (match reference)
#define E_LINKS 131072
#define M_PAIRS 1048576
#define DDIM    64
#define GG      1024
#define RUNITS  256
#define TITER   8

typedef __attribute__((ext_vector_type(8))) short bf16x8;
typedef __attribute__((ext_vector_type(4))) float f32x4;
typedef __attribute__((ext_vector_type(16))) float f32x16;

// HW bf16 convert (v_cvt_pk_bf16_f32, RNE — bit-identical to SW round-to-nearest-even)
__device__ inline unsigned short f2bf(float f){
  __bf16 b = (__bf16)f;
  unsigned short u;
  __builtin_memcpy(&u, &b, 2);
  return u;
}
__device__ inline float bf2f(unsigned short u){
  union { unsigned int u; float f; } v; v.u = ((unsigned int)u) << 16; return v.f;
}
__device__ inline float selu_f(float x){
  return x > 0.f ? 1.0507009873554805f * x
                 : 1.7580993408473766f * (__expf(x) - 1.f);
}
__device__ inline float sigmoid_f(float x){ return 1.f / (1.f + __expf(-x)); }
__device__ inline float tanh_f(float x){
  float xc = fminf(fmaxf(x, -15.f), 15.f);
  float e2 = __expf(2.f * xc);
  return (e2 - 1.f) / (e2 + 1.f);
}

__device__ inline bf16x8 packbf8f(float4 u0, float4 u1){
  bf16x8 r;
  r[0] = (short)f2bf(u0.x); r[1] = (short)f2bf(u0.y);
  r[2] = (short)f2bf(u0.z); r[3] = (short)f2bf(u0.w);
  r[4] = (short)f2bf(u1.x); r[5] = (short)f2bf(u1.y);
  r[6] = (short)f2bf(u1.z); r[7] = (short)f2bf(u1.w);
  return r;
}

__device__ inline f32x16 zero16(){
  f32x16 v;
  #pragma unroll
  for (int i = 0; i < 16; i++) v[i] = 0.f;
  return v;
}

// ---------------- preprocessing ----------------

// Merged: zero counts + graph offsets (sorted gid boundary scan) + weight prep.
// All parts independent; 512 blocks x 256 threads.
__global__ __launch_bounds__(256) void k_misc(const int* __restrict__ gid,
    const float* __restrict__ W_msg,
    const float* __restrict__ gk, const float* __restrict__ grk,
    const float* __restrict__ bi, const float* __restrict__ br,
    int* __restrict__ counts, int* __restrict__ goffs,
    unsigned short* __restrict__ WzrT, unsigned short* __restrict__ WxhT,
    unsigned short* __restrict__ WhhT, unsigned short* __restrict__ WcT,
    float* __restrict__ bzr, float* __restrict__ bxh, float* __restrict__ bhh){
  int i = blockIdx.x * blockDim.x + threadIdx.x;
  counts[i] = 0;
  // graph offsets
  {
    int g = gid[i];
    int gp = (i == 0) ? -1 : gid[i - 1];
    for (int x = gp + 1; x <= g; x++) goffs[x] = i;
    if (i == E_LINKS - 1){
      for (int x = g + 1; x <= GG; x++) goffs[x] = E_LINKS;
    }
  }
  // weights
  if (i < 16384){
    int c = i >> 7, k = i & 127;
    float v = (k < 64) ? gk[k * 192 + c] : grk[(k - 64) * 192 + c];
    WzrT[i] = f2bf(v);
  } else if (i < 20480){
    int j = i - 16384; int c = j >> 6, k = j & 63;
    WxhT[j] = f2bf(gk[k * 192 + 128 + c]);
  } else if (i < 24576){
    int j = i - 20480; int c = j >> 6, k = j & 63;
    WhhT[j] = f2bf(grk[k * 192 + 128 + c]);
  } else if (i < 32768){
    int j = i - 24576; int c = j >> 6, k = j & 63;
    float v = (c < 64) ? W_msg[k * 64 + c] : W_msg[(64 + k) * 64 + (c - 64)];
    WcT[j] = f2bf(v);
  } else if (i < 33024){
    int j = i - 32768;
    if (j < 128) bzr[j] = bi[j] + br[j];
    else if (j < 192) bxh[j - 128] = bi[j];
    else bhh[j - 192] = br[j - 64];
  }
}

__global__ void k_hist(const int* __restrict__ second, int* __restrict__ counts){
  int i = blockIdx.x * blockDim.x + threadIdx.x;
  if (i < M_PAIRS) atomicAdd(&counts[second[i]], 1);
}

__global__ __launch_bounds__(256) void k_scan_reduce(const int* __restrict__ counts,
    int* __restrict__ partials){
  __shared__ int s[256];
  int t = threadIdx.x;
  int i = blockIdx.x * 256 + t;
  s[t] = counts[i];
  __syncthreads();
  #pragma unroll
  for (int off = 128; off > 0; off >>= 1){
    if (t < off) s[t] += s[t + off];
    __syncthreads();
  }
  if (t == 0) partials[blockIdx.x] = s[0];
}

__global__ __launch_bounds__(512) void k_scan_part(int* __restrict__ partials){
  __shared__ int s[512];
  int t = threadIdx.x;
  int v = partials[t];
  s[t] = v;
  __syncthreads();
  for (int off = 1; off < 512; off <<= 1){
    int u = (t >= off) ? s[t - off] : 0;
    __syncthreads();
    s[t] += u;
    __syncthreads();
  }
  partials[t] = s[t] - v;
}

__global__ __launch_bounds__(256) void k_scan_apply(const int* __restrict__ counts,
    const int* __restrict__ partials, int* __restrict__ offsets,
    int* __restrict__ cursor){
  __shared__ int s[256];
  int t = threadIdx.x;
  int i = blockIdx.x * 256 + t;
  int c = counts[i];
  s[t] = c;
  __syncthreads();
  for (int off = 1; off < 256; off <<= 1){
    int u = (t >= off) ? s[t - off] : 0;
    __syncthreads();
    s[t] += u;
    __syncthreads();
  }
  int run = partials[blockIdx.x] + s[t] - c;
  offsets[i] = run;
  cursor[i] = run;
  if (i == E_LINKS - 1) offsets[E_LINKS] = run + c;
}

__global__ void k_scatter(const int* __restrict__ first, const int* __restrict__ second,
    int* __restrict__ cursor, int* __restrict__ srcs){
  int i = blockIdx.x * blockDim.x + threadIdx.x;
  if (i < M_PAIRS){
    int e = second[i];
    int slot = atomicAdd(&cursor[e], 1);
    srcs[slot] = first[i];
  }
}

// ---------------- main loop kernels ----------------

// AB[E,128] = h[E,64] @ Wc[64,128] (+ b_msg on cols>=64); h read as f32.
__global__ __launch_bounds__(256) void k_ab0(const float* __restrict__ hf,
    const unsigned short* __restrict__ WcT, const float* __restrict__ b_msg,
    unsigned short* __restrict__ AB){
  int wave = threadIdx.x >> 6, lane = threadIdx.x & 63;
  int row0 = (blockIdx.x * 4 + wave) * 16;
  int lr = lane & 15, lg = lane >> 4;
  f32x4 acc[8];
  #pragma unroll
  for (int i = 0; i < 8; i++) acc[i] = (f32x4){0.f, 0.f, 0.f, 0.f};
  #pragma unroll
  for (int s = 0; s < 2; s++){
    int kb = s * 32 + lg * 8;
    const float* p = hf + (size_t)(row0 + lr) * 64 + kb;
    bf16x8 a = packbf8f(*(const float4*)p, *(const float4*)(p + 4));
    #pragma unroll
    for (int ct = 0; ct < 8; ct++){
      bf16x8 b = *(const bf16x8*)(WcT + (ct * 16 + lr) * 64 + kb);
      acc[ct] = __builtin_amdgcn_mfma_f32_16x16x32_bf16(a, b, acc[ct], 0, 0, 0);
    }
  }
  #pragma unroll
  for (int ct = 0; ct < 8; ct++){
    int col = ct * 16 + lr;
    float bias = (col >= 64) ? b_msg[col - 64] : 0.f;
    #pragma unroll
    for (int q = 0; q < 4; q++){
      int row = row0 + lg * 4 + q;
      AB[(size_t)row * 128 + col] = f2bf(acc[ct][q] + bias);
    }
  }
}

// agg[e][:] = sum over incoming msgs: selu(A[src] + B[e])
// One wave per edge; 4 lane-groups of 16 each gather one 128B source row
// per iteration (ushort4/lane), 2x unrolled -> 8 rows in flight. (R8-proven)
__global__ __launch_bounds__(256) void k_agg(const unsigned short* __restrict__ AB,
    const int* __restrict__ offsets, const int* __restrict__ srcs,
    unsigned short* __restrict__ agg){
  int wave = threadIdx.x >> 6, lane = threadIdx.x & 63;
  int e = blockIdx.x * 4 + wave;
  int g = lane >> 4, d = lane & 15;

  ushort4 bq = *(const ushort4*)(AB + (size_t)e * 128 + 64 + d * 4);
  float b0 = bf2f(bq.x), b1 = bf2f(bq.y), b2 = bf2f(bq.z), b3 = bf2f(bq.w);

  int beg = offsets[e], end = offsets[e + 1];
  float a0 = 0.f, a1 = 0.f, a2 = 0.f, a3 = 0.f;

  int i = beg + g;
  for (; i + 4 < end; i += 8){
    int s0 = srcs[i];
    int s1 = srcs[i + 4];
    ushort4 q0 = *(const ushort4*)(AB + (size_t)s0 * 128 + d * 4);
    ushort4 q1 = *(const ushort4*)(AB + (size_t)s1 * 128 + d * 4);
    a0 += selu_f(bf2f(q0.x) + b0);
    a1 += selu_f(bf2f(q0.y) + b1);
    a2 += selu_f(bf2f(q0.z) + b2);
    a3 += selu_f(bf2f(q0.w) + b3);
    a0 += selu_f(bf2f(q1.x) + b0);
    a1 += selu_f(bf2f(q1.y) + b1);
    a2 += selu_f(bf2f(q1.z) + b2);
    a3 += selu_f(bf2f(q1.w) + b3);
  }
  if (i < end){
    int s0 = srcs[i];
    ushort4 q0 = *(const ushort4*)(AB + (size_t)s0 * 128 + d * 4);
    a0 += selu_f(bf2f(q0.x) + b0);
    a1 += selu_f(bf2f(q0.y) + b1);
    a2 += selu_f(bf2f(q0.z) + b2);
    a3 += selu_f(bf2f(q0.w) + b3);
  }

  a0 += __shfl_xor(a0, 16, 64); a0 += __shfl_xor(a0, 32, 64);
  a1 += __shfl_xor(a1, 16, 64); a1 += __shfl_xor(a1, 32, 64);
  a2 += __shfl_xor(a2, 16, 64); a2 += __shfl_xor(a2, 32, 64);
  a3 += __shfl_xor(a3, 16, 64); a3 += __shfl_xor(a3, 32, 64);

  if (g == 0){
    ushort4 o;
    o.x = f2bf(a0); o.y = f2bf(a1); o.z = f2bf(a2); o.w = f2bf(a3);
    *(ushort4*)(agg + (size_t)e * 64 + d * 4) = o;
  }
}

// Fused GRU (+ optional AB), 32 rows/wave via 32x32x16 MFMA.
// Layouts: A/B  row|col = lane&31, k = (lane>>5)*8 + j
//          C/D  col = lane&31, row = (reg&3) + 8*(reg>>2) + 4*(lane>>5)
// LDS: per-wave fp32 hold tile hsh[32][68] (8.7KB), REUSED (union) as the
// bf16 transpose tile tsh[32][64] after holds are consumed (barrier-protected).
// LDS/block = 34816 -> 4 blocks/CU; VGPR ~64 -> 16 waves/CU.
template<bool WITH_AB>
__global__ __launch_bounds__(256, 4) void k_fused(const unsigned short* __restrict__ agg,
    const float* h_in, float* h_out,
    const unsigned short* __restrict__ WzrT, const unsigned short* __restrict__ WxhT,
    const unsigned short* __restrict__ WhhT, const unsigned short* __restrict__ WcT,
    const float* __restrict__ bzr, const float* __restrict__ bxh,
    const float* __restrict__ bhh,
    const float* __restrict__ b_msg, unsigned short* __restrict__ AB){
  __shared__ float hsh[4][32][68];   // 34816B; tail-reused as tsh
  int wave = threadIdx.x >> 6, lane = threadIdx.x & 63;
  int row0 = (blockIdx.x * 4 + wave) * 32;
  int lc = lane & 31, lh = lane >> 5;
  unsigned short* tsh = (unsigned short*)&hsh[wave][0][0]; // [32][64] bf16, swizzled

  // ---- A fragments over combined K=128 ([agg | h]) + fp32 hold stash ----
  bf16x8 az[8];
  const unsigned short* arow = agg + (size_t)(row0 + lc) * 64 + lh * 8;
  #pragma unroll
  for (int s = 0; s < 4; s++) az[s] = *(const bf16x8*)(arow + s * 16);
  const float* hrow = h_in + (size_t)(row0 + lc) * 64 + lh * 8;
  #pragma unroll
  for (int s = 0; s < 4; s++){
    float4 u0 = *(const float4*)(hrow + s * 16);
    float4 u1 = *(const float4*)(hrow + s * 16 + 4);
    az[4 + s] = packbf8f(u0, u1);
    *(float4*)(&hsh[wave][lc][s * 16 + lh * 8]) = u0;
    *(float4*)(&hsh[wave][lc][s * 16 + lh * 8 + 4]) = u1;
  }

  // ---- r-gate GEMM (zr tiles 2,3 -> cols 64..127) ----
  f32x16 ar0 = zero16(), ar1 = zero16();
  #pragma unroll
  for (int s = 0; s < 8; s++){
    const unsigned short* wk = WzrT + lh * 8 + s * 16;
    bf16x8 b2 = *(const bf16x8*)(wk + (size_t)(64 + lc) * 128);
    bf16x8 b3 = *(const bf16x8*)(wk + (size_t)(96 + lc) * 128);
    ar0 = __builtin_amdgcn_mfma_f32_32x32x16_bf16(az[s], b2, ar0, 0, 0, 0);
    ar1 = __builtin_amdgcn_mfma_f32_32x32x16_bf16(az[s], b3, ar1, 0, 0, 0);
  }

  float cv[2][16];

  // ---- cols 0..31: xh0 (A=agg), hh0 (A=h) -> cv[0] ----
  {
    f32x16 axh = zero16(), ahh = zero16();
    #pragma unroll
    for (int s = 0; s < 4; s++){
      const unsigned short* wx = WxhT + lh * 8 + s * 16;
      axh = __builtin_amdgcn_mfma_f32_32x32x16_bf16(az[s],
          *(const bf16x8*)(wx + (size_t)lc * 64), axh, 0, 0, 0);
      const unsigned short* wh = WhhT + lh * 8 + s * 16;
      ahh = __builtin_amdgcn_mfma_f32_32x32x16_bf16(az[4 + s],
          *(const bf16x8*)(wh + (size_t)lc * 64), ahh, 0, 0, 0);
    }
    float brv = bzr[64 + lc], bx = bxh[lc], bh = bhh[lc];
    #pragma unroll
    for (int r = 0; r < 16; r++){
      float rr = sigmoid_f(ar0[r] + brv);
      cv[0][r] = tanh_f(axh[r] + bx + rr * (ahh[r] + bh));
    }
  }

  // ---- cols 32..63: xh1, hh1 -> cv[1] ----
  {
    f32x16 axh = zero16(), ahh = zero16();
    #pragma unroll
    for (int s = 0; s < 4; s++){
      const unsigned short* wx = WxhT + lh * 8 + s * 16;
      axh = __builtin_amdgcn_mfma_f32_32x32x16_bf16(az[s],
          *(const bf16x8*)(wx + (size_t)(32 + lc) * 64), axh, 0, 0, 0);
      const unsigned short* wh = WhhT + lh * 8 + s * 16;
      ahh = __builtin_amdgcn_mfma_f32_32x32x16_bf16(az[4 + s],
          *(const bf16x8*)(wh + (size_t)(32 + lc) * 64), ahh, 0, 0, 0);
    }
    float brv = bzr[64 + 32 + lc], bx = bxh[32 + lc], bh = bhh[32 + lc];
    #pragma unroll
    for (int r = 0; r < 16; r++){
      float rr = sigmoid_f(ar1[r] + brv);
      cv[1][r] = tanh_f(axh[r] + bx + rr * (ahh[r] + bh));
    }
  }

  // ---- z-gate GEMM (zr tiles 0,1 -> cols 0..63) ----
  f32x16 azt0 = zero16(), azt1 = zero16();
  #pragma unroll
  for (int s = 0; s < 8; s++){
    const unsigned short* wk = WzrT + lh * 8 + s * 16;
    bf16x8 b0 = *(const bf16x8*)(wk + (size_t)lc * 128);
    bf16x8 b1 = *(const bf16x8*)(wk + (size_t)(32 + lc) * 128);
    azt0 = __builtin_amdgcn_mfma_f32_32x32x16_bf16(az[s], b0, azt0, 0, 0, 0);
    azt1 = __builtin_amdgcn_mfma_f32_32x32x16_bf16(az[s], b1, azt1, 0, 0, 0);
  }

  // ---- phase 1: read holds from hsh, fold z -> final v (into cv) ----
  {
    float bz0 = bzr[lc], bz1 = bzr[32 + lc];
    #pragma unroll
    for (int r = 0; r < 16; r++){
      int rl = (r & 3) + 8 * (r >> 2) + 4 * lh;
      float h0 = hsh[wave][rl][lc];
      float h1 = hsh[wave][rl][32 + lc];
      float z0 = sigmoid_f(azt0[r] + bz0);
      float z1 = sigmoid_f(azt1[r] + bz1);
      cv[0][r] = z0 * h0 + (1.f - z0) * cv[0][r];
      cv[1][r] = z1 * h1 + (1.f - z1) * cv[1][r];
    }
  }

  __syncthreads();   // all hsh reads complete before tsh overwrites the space

  // ---- phase 2: write h_out (global) + tsh (LDS, swizzled) ----
  {
    int j0 = lc, j1 = 32 + lc;
    #pragma unroll
    for (int r = 0; r < 16; r++){
      int rl = (r & 3) + 8 * (r >> 2) + 4 * lh;
      size_t base = (size_t)(row0 + rl) * 64;
      h_out[base + j0] = cv[0][r];
      h_out[base + j1] = cv[1][r];
      if (WITH_AB){
        tsh[rl * 64 + (((j0 >> 3) ^ (rl & 7)) << 3) + (j0 & 7)] = f2bf(cv[0][r]);
        tsh[rl * 64 + (((j1 >> 3) ^ (rl & 7)) << 3) + (j1 & 7)] = f2bf(cv[1][r]);
      }
    }
  }

  if (WITH_AB){
    // AB GEMM: M=32, N=128, K=64; A = hn from swizzled tsh
    f32x16 acc[4];
    #pragma unroll
    for (int i = 0; i < 4; i++) acc[i] = zero16();
    #pragma unroll
    for (int s = 0; s < 4; s++){
      int blk = ((s * 2 + lh) ^ (lc & 7)) << 3;
      bf16x8 a = *(const bf16x8*)(&tsh[lc * 64 + blk]);
      const unsigned short* wc = WcT + lh * 8 + s * 16;
      #pragma unroll
      for (int ct = 0; ct < 4; ct++){
        bf16x8 b = *(const bf16x8*)(wc + (size_t)(ct * 32 + lc) * 64);
        acc[ct] = __builtin_amdgcn_mfma_f32_32x32x16_bf16(a, b, acc[ct], 0, 0, 0);
      }
    }
    #pragma unroll
    for (int ct = 0; ct < 4; ct++){
      int col = ct * 32 + lc;
      float bias = (col >= 64) ? b_msg[col - 64] : 0.f;
      #pragma unroll
      for (int r = 0; r < 16; r++){
        int rl = (r & 3) + 8 * (r >> 2) + 4 * lh;
        AB[(size_t)(row0 + rl) * 128 + col] = f2bf(acc[ct][r] + bias);
      }
    }
  }
}

// ---------------- readout (segment sum fused into MLP) ----------------

__global__ __launch_bounds__(256) void k_mlp(const float* __restrict__ hf,
    const int* __restrict__ goffs,
    const float* __restrict__ W1, const float* __restrict__ b1,
    const float* __restrict__ W2, const float* __restrict__ b2,
    const float* __restrict__ W3, const float* __restrict__ b3,
    float* __restrict__ out){
  __shared__ float part[4][64];
  __shared__ float sg[64];
  __shared__ float sr1[256];
  __shared__ float sr2[256];
  __shared__ float wsum[4];
  int g = blockIdx.x, t = threadIdx.x;
  int wave = t >> 6, lane = t & 63;

  // segment sum: 4 waves stride the segment rows
  int beg = goffs[g], end = goffs[g + 1];
  float acc = 0.f;
  for (int e = beg + wave; e < end; e += 4) acc += hf[(size_t)e * 64 + lane];
  part[wave][lane] = acc;
  __syncthreads();
  if (t < 64) sg[t] = part[0][t] + part[1][t] + part[2][t] + part[3][t];
  __syncthreads();

  float a = b1[t];
  #pragma unroll
  for (int k = 0; k < 64; k++) a += sg[k] * W1[k * 256 + t];
  sr1[t] = selu_f(a);
  __syncthreads();
  float b = b2[t];
  for (int k = 0; k < 256; k++) b += sr1[k] * W2[k * 256 + t];
  sr2[t] = selu_f(b);
  __syncthreads();
  float v = sr2[t] * W3[t];
  for (int off = 32; off > 0; off >>= 1) v += __shfl_down(v, off, 64);
  if ((t & 63) == 0) wsum[t >> 6] = v;
  __syncthreads();
  if (t == 0) out[g] = wsum[0] + wsum[1] + wsum[2] + wsum[3] + b3[0];
}

// ---------------- host ----------------

static inline size_t alignup(size_t x){ return (x + 255) & ~(size_t)255; }

extern "C" void kernel_launch(void* const* d_in, const int* in_sizes, int n_in,
                              void* d_out, int out_size, void* d_ws, size_t ws_size,
                              hipStream_t stream) {
  const float* states_action = (const float*)d_in[0];
  const int*   graph_ids     = (const int*)d_in[1];
  const int*   first         = (const int*)d_in[2];
  const int*   second        = (const int*)d_in[3];
  const float* W_msg         = (const float*)d_in[5];
  const float* b_msg         = (const float*)d_in[6];
  const float* gk            = (const float*)d_in[7];
  const float* grk           = (const float*)d_in[8];
  const float* bi            = (const float*)d_in[9];
  const float* br            = (const float*)d_in[10];
  const float* W1            = (const float*)d_in[11];
  const float* b1            = (const float*)d_in[12];
  const float* W2            = (const float*)d_in[13];
  const float* b2            = (const float*)d_in[14];
  const float* W3            = (const float*)d_in[15];
  const float* b3            = (const float*)d_in[16];
  float* out = (float*)d_out;

  char* ws = (char*)d_ws;
  size_t off = 0;
  float*          h_f32  = (float*)(ws + off);          off += alignup((size_t)E_LINKS * 64 * 4);
  unsigned short* aggb   = (unsigned short*)(ws + off); off += alignup((size_t)E_LINKS * 64 * 2);
  unsigned short* AB     = (unsigned short*)(ws + off); off += alignup((size_t)E_LINKS * 128 * 2);
  unsigned short* WzrT   = (unsigned short*)(ws + off); off += alignup(128 * 128 * 2);
  unsigned short* WxhT   = (unsigned short*)(ws + off); off += alignup(64 * 64 * 2);
  unsigned short* WhhT   = (unsigned short*)(ws + off); off += alignup(64 * 64 * 2);
  unsigned short* WcT    = (unsigned short*)(ws + off); off += alignup(128 * 64 * 2);
  float*          bzr    = (float*)(ws + off);          off += alignup(128 * 4);
  float*          bxhv   = (float*)(ws + off);          off += alignup(64 * 4);
  float*          bhhv   = (float*)(ws + off);          off += alignup(64 * 4);
  int*            counts = (int*)(ws + off);            off += alignup((size_t)E_LINKS * 4);
  int*            offs   = (int*)(ws + off);            off += alignup(((size_t)E_LINKS + 1) * 4);
  int*            cursor = (int*)(ws + off);            off += alignup((size_t)E_LINKS * 4);
  int*            srcs   = (int*)(ws + off);            off += alignup((size_t)M_PAIRS * 4);
  int*            parts  = (int*)(ws + off);            off += alignup(512 * 4);
  int*            goffs  = (int*)(ws + off);            off += alignup(((size_t)GG + 1) * 4);

  dim3 b256(256);

  // preprocessing
  k_misc<<<dim3(512), b256, 0, stream>>>(graph_ids, W_msg, gk, grk, bi, br,
      counts, goffs, WzrT, WxhT, WhhT, WcT, bzr, bxhv, bhhv);
  k_hist<<<dim3(M_PAIRS / 256), b256, 0, stream>>>(second, counts);
  k_scan_reduce<<<dim3(512), b256, 0, stream>>>(counts, parts);
  k_scan_part<<<dim3(1), dim3(512), 0, stream>>>(parts);
  k_scan_apply<<<dim3(512), b256, 0, stream>>>(counts, parts, offs, cursor);
  k_scatter<<<dim3(M_PAIRS / 256), b256, 0, stream>>>(first, second, cursor, srcs);

  // t=0 message precompute from initial h (= states_action)
  k_ab0<<<dim3(E_LINKS / 64), b256, 0, stream>>>(states_action, WcT, b_msg, AB);

  // message passing: split kernels, single AB buffer (L2-friendly)
  for (int t = 0; t < TITER; t++){
    k_agg<<<dim3(E_LINKS / 4), b256, 0, stream>>>(AB, offs, srcs, aggb);
    const float* h_in = (t == 0) ? states_action : h_f32;
    if (t < TITER - 1)
      k_fused<true><<<dim3(E_LINKS / 128), b256, 0, stream>>>(aggb, h_in, h_f32,
          WzrT, WxhT, WhhT, WcT, bzr, bxhv, bhhv, b_msg, AB);
    else
      k_fused<false><<<dim3(E_LINKS / 128), b256, 0, stream>>>(aggb, h_in, h_f32,
          WzrT, WxhT, WhhT, WcT, bzr, bxhv, bhhv, b_msg, AB);
  }

  // readout
  k_mlp<<<dim3(GG), b256, 0, stream>>>(h_f32, goffs, W1, b1, W2, b2, W3, b3, out);
}

// Round 13
// 942.878 us; speedup vs baseline: 2.1927x; 1.0169x over previous
//
#include <hip/hip_runtime.h>
#include <hip/hip_bf16.h>

// Problem constants (match reference)
#define E_LINKS 131072
#define M_PAIRS 1048576
#define DDIM    64
#define GG      1024
#define RUNITS  256
#define TITER   8

typedef __attribute__((ext_vector_type(8))) short bf16x8;
typedef __attribute__((ext_vector_type(4))) float f32x4;
typedef __attribute__((ext_vector_type(16))) float f32x16;

// HW bf16 convert (RNE)
__device__ inline unsigned short f2bf(float f){
  __bf16 b = (__bf16)f;
  unsigned short u;
  __builtin_memcpy(&u, &b, 2);
  return u;
}
__device__ inline float bf2f(unsigned short u){
  union { unsigned int u; float f; } v; v.u = ((unsigned int)u) << 16; return v.f;
}
__device__ inline float selu_f(float x){
  return x > 0.f ? 1.0507009873554805f * x
                 : 1.7580993408473766f * (__expf(x) - 1.f);
}
__device__ inline float sigmoid_f(float x){ return 1.f / (1.f + __expf(-x)); }
__device__ inline float tanh_f(float x){
  float xc = fminf(fmaxf(x, -15.f), 15.f);
  float e2 = __expf(2.f * xc);
  return (e2 - 1.f) / (e2 + 1.f);
}

__device__ inline bf16x8 packbf8f(float4 u0, float4 u1){
  bf16x8 r;
  r[0] = (short)f2bf(u0.x); r[1] = (short)f2bf(u0.y);
  r[2] = (short)f2bf(u0.z); r[3] = (short)f2bf(u0.w);
  r[4] = (short)f2bf(u1.x); r[5] = (short)f2bf(u1.y);
  r[6] = (short)f2bf(u1.z); r[7] = (short)f2bf(u1.w);
  return r;
}

__device__ inline f32x16 zero16(){
  f32x16 v;
  #pragma unroll
  for (int i = 0; i < 16; i++) v[i] = 0.f;
  return v;
}

// ---------------- preprocessing ----------------

// Merged: zero counts + graph offsets + weight prep. 512 blocks x 256 threads.
__global__ __launch_bounds__(256) void k_misc(const int* __restrict__ gid,
    const float* __restrict__ W_msg,
    const float* __restrict__ gk, const float* __restrict__ grk,
    const float* __restrict__ bi, const float* __restrict__ br,
    int* __restrict__ counts, int* __restrict__ goffs,
    unsigned short* __restrict__ WzrT, unsigned short* __restrict__ WxhT,
    unsigned short* __restrict__ WhhT, unsigned short* __restrict__ WcT,
    float* __restrict__ bzr, float* __restrict__ bxh, float* __restrict__ bhh){
  int i = blockIdx.x * blockDim.x + threadIdx.x;
  counts[i] = 0;
  {
    int g = gid[i];
    int gp = (i == 0) ? -1 : gid[i - 1];
    for (int x = gp + 1; x <= g; x++) goffs[x] = i;
    if (i == E_LINKS - 1){
      for (int x = g + 1; x <= GG; x++) goffs[x] = E_LINKS;
    }
  }
  if (i < 16384){
    int c = i >> 7, k = i & 127;
    float v = (k < 64) ? gk[k * 192 + c] : grk[(k - 64) * 192 + c];
    WzrT[i] = f2bf(v);
  } else if (i < 20480){
    int j = i - 16384; int c = j >> 6, k = j & 63;
    WxhT[j] = f2bf(gk[k * 192 + 128 + c]);
  } else if (i < 24576){
    int j = i - 20480; int c = j >> 6, k = j & 63;
    WhhT[j] = f2bf(grk[k * 192 + 128 + c]);
  } else if (i < 32768){
    int j = i - 24576; int c = j >> 6, k = j & 63;
    float v = (c < 64) ? W_msg[k * 64 + c] : W_msg[(64 + k) * 64 + (c - 64)];
    WcT[j] = f2bf(v);
  } else if (i < 33024){
    int j = i - 32768;
    if (j < 128) bzr[j] = bi[j] + br[j];
    else if (j < 192) bxh[j - 128] = bi[j];
    else bhh[j - 192] = br[j - 64];
  }
}

// one-time: states_action f32 -> bf16 h state
__global__ __launch_bounds__(256) void k_h0(const float* __restrict__ sa,
    unsigned short* __restrict__ hb){
  int i = blockIdx.x * blockDim.x + threadIdx.x;   // E*64/4 threads
  float4 v = *(const float4*)(sa + (size_t)i * 4);
  ushort4 o;
  o.x = f2bf(v.x); o.y = f2bf(v.y); o.z = f2bf(v.z); o.w = f2bf(v.w);
  *(ushort4*)(hb + (size_t)i * 4) = o;
}

__global__ void k_hist(const int* __restrict__ second, int* __restrict__ counts){
  int i = blockIdx.x * blockDim.x + threadIdx.x;
  if (i < M_PAIRS) atomicAdd(&counts[second[i]], 1);
}

__global__ __launch_bounds__(256) void k_scan_reduce(const int* __restrict__ counts,
    int* __restrict__ partials){
  __shared__ int s[256];
  int t = threadIdx.x;
  int i = blockIdx.x * 256 + t;
  s[t] = counts[i];
  __syncthreads();
  #pragma unroll
  for (int off = 128; off > 0; off >>= 1){
    if (t < off) s[t] += s[t + off];
    __syncthreads();
  }
  if (t == 0) partials[blockIdx.x] = s[0];
}

__global__ __launch_bounds__(512) void k_scan_part(int* __restrict__ partials){
  __shared__ int s[512];
  int t = threadIdx.x;
  int v = partials[t];
  s[t] = v;
  __syncthreads();
  for (int off = 1; off < 512; off <<= 1){
    int u = (t >= off) ? s[t - off] : 0;
    __syncthreads();
    s[t] += u;
    __syncthreads();
  }
  partials[t] = s[t] - v;
}

__global__ __launch_bounds__(256) void k_scan_apply(const int* __restrict__ counts,
    const int* __restrict__ partials, int* __restrict__ offsets,
    int* __restrict__ cursor){
  __shared__ int s[256];
  int t = threadIdx.x;
  int i = blockIdx.x * 256 + t;
  int c = counts[i];
  s[t] = c;
  __syncthreads();
  for (int off = 1; off < 256; off <<= 1){
    int u = (t >= off) ? s[t - off] : 0;
    __syncthreads();
    s[t] += u;
    __syncthreads();
  }
  int run = partials[blockIdx.x] + s[t] - c;
  offsets[i] = run;
  cursor[i] = run;
  if (i == E_LINKS - 1) offsets[E_LINKS] = run + c;
}

__global__ void k_scatter(const int* __restrict__ first, const int* __restrict__ second,
    int* __restrict__ cursor, int* __restrict__ srcs){
  int i = blockIdx.x * blockDim.x + threadIdx.x;
  if (i < M_PAIRS){
    int e = second[i];
    int slot = atomicAdd(&cursor[e], 1);
    srcs[slot] = first[i];
  }
}

// ---------------- main loop kernels ----------------

// AB[E,128] = h[E,64] @ Wc[64,128] (+ b_msg on cols>=64); h read as f32 (t=0 only).
__global__ __launch_bounds__(256) void k_ab0(const float* __restrict__ hf,
    const unsigned short* __restrict__ WcT, const float* __restrict__ b_msg,
    unsigned short* __restrict__ AB){
  int wave = threadIdx.x >> 6, lane = threadIdx.x & 63;
  int row0 = (blockIdx.x * 4 + wave) * 16;
  int lr = lane & 15, lg = lane >> 4;
  f32x4 acc[8];
  #pragma unroll
  for (int i = 0; i < 8; i++) acc[i] = (f32x4){0.f, 0.f, 0.f, 0.f};
  #pragma unroll
  for (int s = 0; s < 2; s++){
    int kb = s * 32 + lg * 8;
    const float* p = hf + (size_t)(row0 + lr) * 64 + kb;
    bf16x8 a = packbf8f(*(const float4*)p, *(const float4*)(p + 4));
    #pragma unroll
    for (int ct = 0; ct < 8; ct++){
      bf16x8 b = *(const bf16x8*)(WcT + (ct * 16 + lr) * 64 + kb);
      acc[ct] = __builtin_amdgcn_mfma_f32_16x16x32_bf16(a, b, acc[ct], 0, 0, 0);
    }
  }
  #pragma unroll
  for (int ct = 0; ct < 8; ct++){
    int col = ct * 16 + lr;
    float bias = (col >= 64) ? b_msg[col - 64] : 0.f;
    #pragma unroll
    for (int q = 0; q < 4; q++){
      int row = row0 + lg * 4 + q;
      AB[(size_t)row * 128 + col] = f2bf(acc[ct][q] + bias);
    }
  }
}

// agg[e][:] = sum over incoming msgs: selu(A[src] + B[e])   (R8-proven form)
__global__ __launch_bounds__(256) void k_agg(const unsigned short* __restrict__ AB,
    const int* __restrict__ offsets, const int* __restrict__ srcs,
    unsigned short* __restrict__ agg){
  int wave = threadIdx.x >> 6, lane = threadIdx.x & 63;
  int e = blockIdx.x * 4 + wave;
  int g = lane >> 4, d = lane & 15;

  ushort4 bq = *(const ushort4*)(AB + (size_t)e * 128 + 64 + d * 4);
  float b0 = bf2f(bq.x), b1 = bf2f(bq.y), b2 = bf2f(bq.z), b3 = bf2f(bq.w);

  int beg = offsets[e], end = offsets[e + 1];
  float a0 = 0.f, a1 = 0.f, a2 = 0.f, a3 = 0.f;

  int i = beg + g;
  for (; i + 4 < end; i += 8){
    int s0 = srcs[i];
    int s1 = srcs[i + 4];
    ushort4 q0 = *(const ushort4*)(AB + (size_t)s0 * 128 + d * 4);
    ushort4 q1 = *(const ushort4*)(AB + (size_t)s1 * 128 + d * 4);
    a0 += selu_f(bf2f(q0.x) + b0);
    a1 += selu_f(bf2f(q0.y) + b1);
    a2 += selu_f(bf2f(q0.z) + b2);
    a3 += selu_f(bf2f(q0.w) + b3);
    a0 += selu_f(bf2f(q1.x) + b0);
    a1 += selu_f(bf2f(q1.y) + b1);
    a2 += selu_f(bf2f(q1.z) + b2);
    a3 += selu_f(bf2f(q1.w) + b3);
  }
  if (i < end){
    int s0 = srcs[i];
    ushort4 q0 = *(const ushort4*)(AB + (size_t)s0 * 128 + d * 4);
    a0 += selu_f(bf2f(q0.x) + b0);
    a1 += selu_f(bf2f(q0.y) + b1);
    a2 += selu_f(bf2f(q0.z) + b2);
    a3 += selu_f(bf2f(q0.w) + b3);
  }

  a0 += __shfl_xor(a0, 16, 64); a0 += __shfl_xor(a0, 32, 64);
  a1 += __shfl_xor(a1, 16, 64); a1 += __shfl_xor(a1, 32, 64);
  a2 += __shfl_xor(a2, 16, 64); a2 += __shfl_xor(a2, 32, 64);
  a3 += __shfl_xor(a3, 16, 64); a3 += __shfl_xor(a3, 32, 64);

  if (g == 0){
    ushort4 o;
    o.x = f2bf(a0); o.y = f2bf(a1); o.z = f2bf(a2); o.w = f2bf(a3);
    *(ushort4*)(agg + (size_t)e * 64 + d * 4) = o;
  }
}

// Fused GRU (+ optional AB), 32 rows/wave via 32x32x16 MFMA.
// h state stored bf16, updated IN PLACE (each wave owns its 32 rows; reads
// happen in the fragment phase, writes after the barrier).
// LDS: per-wave fp32 hold tile hsh[32][68] (8.7KB) built from the bf16 h
// loads, REUSED (union) as the bf16 transpose tile tsh[32][64] after holds
// are consumed (barrier-protected). 4 blocks/CU; VGPR ~64 -> 16 waves/CU.
template<bool WITH_AB>
__global__ __launch_bounds__(256, 4) void k_fused(const unsigned short* __restrict__ agg,
    unsigned short* h,   // bf16 state, in-place
    const unsigned short* __restrict__ WzrT, const unsigned short* __restrict__ WxhT,
    const unsigned short* __restrict__ WhhT, const unsigned short* __restrict__ WcT,
    const float* __restrict__ bzr, const float* __restrict__ bxh,
    const float* __restrict__ bhh,
    const float* __restrict__ b_msg, unsigned short* __restrict__ AB){
  __shared__ float hsh[4][32][68];   // 34816B; tail-reused as tsh
  int wave = threadIdx.x >> 6, lane = threadIdx.x & 63;
  int row0 = (blockIdx.x * 4 + wave) * 32;
  int lc = lane & 31, lh = lane >> 5;
  unsigned short* tsh = (unsigned short*)&hsh[wave][0][0]; // [32][64] bf16, swizzled

  // ---- A fragments over combined K=128 ([agg | h]) + fp32 hold stash ----
  bf16x8 az[8];
  const unsigned short* arow = agg + (size_t)(row0 + lc) * 64 + lh * 8;
  #pragma unroll
  for (int s = 0; s < 4; s++) az[s] = *(const bf16x8*)(arow + s * 16);
  const unsigned short* hrow = h + (size_t)(row0 + lc) * 64 + lh * 8;
  #pragma unroll
  for (int s = 0; s < 4; s++){
    bf16x8 hv = *(const bf16x8*)(hrow + s * 16);
    az[4 + s] = hv;
    float4 u0, u1;
    u0.x = bf2f((unsigned short)hv[0]); u0.y = bf2f((unsigned short)hv[1]);
    u0.z = bf2f((unsigned short)hv[2]); u0.w = bf2f((unsigned short)hv[3]);
    u1.x = bf2f((unsigned short)hv[4]); u1.y = bf2f((unsigned short)hv[5]);
    u1.z = bf2f((unsigned short)hv[6]); u1.w = bf2f((unsigned short)hv[7]);
    *(float4*)(&hsh[wave][lc][s * 16 + lh * 8]) = u0;
    *(float4*)(&hsh[wave][lc][s * 16 + lh * 8 + 4]) = u1;
  }

  // ---- r-gate GEMM (zr tiles 2,3 -> cols 64..127) ----
  f32x16 ar0 = zero16(), ar1 = zero16();
  #pragma unroll
  for (int s = 0; s < 8; s++){
    const unsigned short* wk = WzrT + lh * 8 + s * 16;
    bf16x8 b2 = *(const bf16x8*)(wk + (size_t)(64 + lc) * 128);
    bf16x8 b3 = *(const bf16x8*)(wk + (size_t)(96 + lc) * 128);
    ar0 = __builtin_amdgcn_mfma_f32_32x32x16_bf16(az[s], b2, ar0, 0, 0, 0);
    ar1 = __builtin_amdgcn_mfma_f32_32x32x16_bf16(az[s], b3, ar1, 0, 0, 0);
  }

  float cv[2][16];

  // ---- cols 0..31: xh0 (A=agg), hh0 (A=h) -> cv[0] ----
  {
    f32x16 axh = zero16(), ahh = zero16();
    #pragma unroll
    for (int s = 0; s < 4; s++){
      const unsigned short* wx = WxhT + lh * 8 + s * 16;
      axh = __builtin_amdgcn_mfma_f32_32x32x16_bf16(az[s],
          *(const bf16x8*)(wx + (size_t)lc * 64), axh, 0, 0, 0);
      const unsigned short* wh = WhhT + lh * 8 + s * 16;
      ahh = __builtin_amdgcn_mfma_f32_32x32x16_bf16(az[4 + s],
          *(const bf16x8*)(wh + (size_t)lc * 64), ahh, 0, 0, 0);
    }
    float brv = bzr[64 + lc], bx = bxh[lc], bh = bhh[lc];
    #pragma unroll
    for (int r = 0; r < 16; r++){
      float rr = sigmoid_f(ar0[r] + brv);
      cv[0][r] = tanh_f(axh[r] + bx + rr * (ahh[r] + bh));
    }
  }

  // ---- cols 32..63: xh1, hh1 -> cv[1] ----
  {
    f32x16 axh = zero16(), ahh = zero16();
    #pragma unroll
    for (int s = 0; s < 4; s++){
      const unsigned short* wx = WxhT + lh * 8 + s * 16;
      axh = __builtin_amdgcn_mfma_f32_32x32x16_bf16(az[s],
          *(const bf16x8*)(wx + (size_t)(32 + lc) * 64), axh, 0, 0, 0);
      const unsigned short* wh = WhhT + lh * 8 + s * 16;
      ahh = __builtin_amdgcn_mfma_f32_32x32x16_bf16(az[4 + s],
          *(const bf16x8*)(wh + (size_t)(32 + lc) * 64), ahh, 0, 0, 0);
    }
    float brv = bzr[64 + 32 + lc], bx = bxh[32 + lc], bh = bhh[32 + lc];
    #pragma unroll
    for (int r = 0; r < 16; r++){
      float rr = sigmoid_f(ar1[r] + brv);
      cv[1][r] = tanh_f(axh[r] + bx + rr * (ahh[r] + bh));
    }
  }

  // ---- z-gate GEMM (zr tiles 0,1 -> cols 0..63) ----
  f32x16 azt0 = zero16(), azt1 = zero16();
  #pragma unroll
  for (int s = 0; s < 8; s++){
    const unsigned short* wk = WzrT + lh * 8 + s * 16;
    bf16x8 b0 = *(const bf16x8*)(wk + (size_t)lc * 128);
    bf16x8 b1 = *(const bf16x8*)(wk + (size_t)(32 + lc) * 128);
    azt0 = __builtin_amdgcn_mfma_f32_32x32x16_bf16(az[s], b0, azt0, 0, 0, 0);
    azt1 = __builtin_amdgcn_mfma_f32_32x32x16_bf16(az[s], b1, azt1, 0, 0, 0);
  }

  // ---- phase 1: read holds from hsh, fold z -> final v (into cv) ----
  {
    float bz0 = bzr[lc], bz1 = bzr[32 + lc];
    #pragma unroll
    for (int r = 0; r < 16; r++){
      int rl = (r & 3) + 8 * (r >> 2) + 4 * lh;
      float h0 = hsh[wave][rl][lc];
      float h1 = hsh[wave][rl][32 + lc];
      float z0 = sigmoid_f(azt0[r] + bz0);
      float z1 = sigmoid_f(azt1[r] + bz1);
      cv[0][r] = z0 * h0 + (1.f - z0) * cv[0][r];
      cv[1][r] = z1 * h1 + (1.f - z1) * cv[1][r];
    }
  }

  __syncthreads();   // all hsh reads complete before tsh overwrites the space

  // ---- phase 2: write h (bf16, in place) + tsh (LDS, swizzled) ----
  {
    int j0 = lc, j1 = 32 + lc;
    #pragma unroll
    for (int r = 0; r < 16; r++){
      int rl = (r & 3) + 8 * (r >> 2) + 4 * lh;
      size_t base = (size_t)(row0 + rl) * 64;
      unsigned short v0 = f2bf(cv[0][r]);
      unsigned short v1 = f2bf(cv[1][r]);
      h[base + j0] = v0;
      h[base + j1] = v1;
      if (WITH_AB){
        tsh[rl * 64 + (((j0 >> 3) ^ (rl & 7)) << 3) + (j0 & 7)] = v0;
        tsh[rl * 64 + (((j1 >> 3) ^ (rl & 7)) << 3) + (j1 & 7)] = v1;
      }
    }
  }

  if (WITH_AB){
    // AB GEMM: M=32, N=128, K=64; A = hn from swizzled tsh
    f32x16 acc[4];
    #pragma unroll
    for (int i = 0; i < 4; i++) acc[i] = zero16();
    #pragma unroll
    for (int s = 0; s < 4; s++){
      int blk = ((s * 2 + lh) ^ (lc & 7)) << 3;
      bf16x8 a = *(const bf16x8*)(&tsh[lc * 64 + blk]);
      const unsigned short* wc = WcT + lh * 8 + s * 16;
      #pragma unroll
      for (int ct = 0; ct < 4; ct++){
        bf16x8 b = *(const bf16x8*)(wc + (size_t)(ct * 32 + lc) * 64);
        acc[ct] = __builtin_amdgcn_mfma_f32_32x32x16_bf16(a, b, acc[ct], 0, 0, 0);
      }
    }
    #pragma unroll
    for (int ct = 0; ct < 4; ct++){
      int col = ct * 32 + lc;
      float bias = (col >= 64) ? b_msg[col - 64] : 0.f;
      #pragma unroll
      for (int r = 0; r < 16; r++){
        int rl = (r & 3) + 8 * (r >> 2) + 4 * lh;
        AB[(size_t)(row0 + rl) * 128 + col] = f2bf(acc[ct][r] + bias);
      }
    }
  }
}

// ---------------- readout (segment sum fused into MLP) ----------------

__global__ __launch_bounds__(256) void k_mlp(const unsigned short* __restrict__ hb,
    const int* __restrict__ goffs,
    const float* __restrict__ W1, const float* __restrict__ b1,
    const float* __restrict__ W2, const float* __restrict__ b2,
    const float* __restrict__ W3, const float* __restrict__ b3,
    float* __restrict__ out){
  __shared__ float part[4][64];
  __shared__ float sg[64];
  __shared__ float sr1[256];
  __shared__ float sr2[256];
  __shared__ float wsum[4];
  int g = blockIdx.x, t = threadIdx.x;
  int wave = t >> 6, lane = t & 63;

  int beg = goffs[g], end = goffs[g + 1];
  float acc = 0.f;
  for (int e = beg + wave; e < end; e += 4) acc += bf2f(hb[(size_t)e * 64 + lane]);
  part[wave][lane] = acc;
  __syncthreads();
  if (t < 64) sg[t] = part[0][t] + part[1][t] + part[2][t] + part[3][t];
  __syncthreads();

  float a = b1[t];
  #pragma unroll
  for (int k = 0; k < 64; k++) a += sg[k] * W1[k * 256 + t];
  sr1[t] = selu_f(a);
  __syncthreads();
  float b = b2[t];
  for (int k = 0; k < 256; k++) b += sr1[k] * W2[k * 256 + t];
  sr2[t] = selu_f(b);
  __syncthreads();
  float v = sr2[t] * W3[t];
  for (int off = 32; off > 0; off >>= 1) v += __shfl_down(v, off, 64);
  if ((t & 63) == 0) wsum[t >> 6] = v;
  __syncthreads();
  if (t == 0) out[g] = wsum[0] + wsum[1] + wsum[2] + wsum[3] + b3[0];
}

// ---------------- host ----------------

static inline size_t alignup(size_t x){ return (x + 255) & ~(size_t)255; }

extern "C" void kernel_launch(void* const* d_in, const int* in_sizes, int n_in,
                              void* d_out, int out_size, void* d_ws, size_t ws_size,
                              hipStream_t stream) {
  const float* states_action = (const float*)d_in[0];
  const int*   graph_ids     = (const int*)d_in[1];
  const int*   first         = (const int*)d_in[2];
  const int*   second        = (const int*)d_in[3];
  const float* W_msg         = (const float*)d_in[5];
  const float* b_msg         = (const float*)d_in[6];
  const float* gk            = (const float*)d_in[7];
  const float* grk           = (const float*)d_in[8];
  const float* bi            = (const float*)d_in[9];
  const float* br            = (const float*)d_in[10];
  const float* W1            = (const float*)d_in[11];
  const float* b1            = (const float*)d_in[12];
  const float* W2            = (const float*)d_in[13];
  const float* b2            = (const float*)d_in[14];
  const float* W3            = (const float*)d_in[15];
  const float* b3            = (const float*)d_in[16];
  float* out = (float*)d_out;

  char* ws = (char*)d_ws;
  size_t off = 0;
  unsigned short* h_bf   = (unsigned short*)(ws + off); off += alignup((size_t)E_LINKS * 64 * 2);
  unsigned short* aggb   = (unsigned short*)(ws + off); off += alignup((size_t)E_LINKS * 64 * 2);
  unsigned short* AB     = (unsigned short*)(ws + off); off += alignup((size_t)E_LINKS * 128 * 2);
  unsigned short* WzrT   = (unsigned short*)(ws + off); off += alignup(128 * 128 * 2);
  unsigned short* WxhT   = (unsigned short*)(ws + off); off += alignup(64 * 64 * 2);
  unsigned short* WhhT   = (unsigned short*)(ws + off); off += alignup(64 * 64 * 2);
  unsigned short* WcT    = (unsigned short*)(ws + off); off += alignup(128 * 64 * 2);
  float*          bzr    = (float*)(ws + off);          off += alignup(128 * 4);
  float*          bxhv   = (float*)(ws + off);          off += alignup(64 * 4);
  float*          bhhv   = (float*)(ws + off);          off += alignup(64 * 4);
  int*            counts = (int*)(ws + off);            off += alignup((size_t)E_LINKS * 4);
  int*            offs   = (int*)(ws + off);            off += alignup(((size_t)E_LINKS + 1) * 4);
  int*            cursor = (int*)(ws + off);            off += alignup((size_t)E_LINKS * 4);
  int*            srcs   = (int*)(ws + off);            off += alignup((size_t)M_PAIRS * 4);
  int*            parts  = (int*)(ws + off);            off += alignup(512 * 4);
  int*            goffs  = (int*)(ws + off);            off += alignup(((size_t)GG + 1) * 4);

  dim3 b256(256);

  // preprocessing
  k_misc<<<dim3(512), b256, 0, stream>>>(graph_ids, W_msg, gk, grk, bi, br,
      counts, goffs, WzrT, WxhT, WhhT, WcT, bzr, bxhv, bhhv);
  k_hist<<<dim3(M_PAIRS / 256), b256, 0, stream>>>(second, counts);
  k_scan_reduce<<<dim3(512), b256, 0, stream>>>(counts, parts);
  k_scan_part<<<dim3(1), dim3(512), 0, stream>>>(parts);
  k_scan_apply<<<dim3(512), b256, 0, stream>>>(counts, parts, offs, cursor);
  k_scatter<<<dim3(M_PAIRS / 256), b256, 0, stream>>>(first, second, cursor, srcs);

  // h state init (bf16) + t=0 message precompute from f32 states_action
  k_h0<<<dim3(E_LINKS * 64 / 1024), b256, 0, stream>>>(states_action, h_bf);
  k_ab0<<<dim3(E_LINKS / 64), b256, 0, stream>>>(states_action, WcT, b_msg, AB);

  // message passing: split kernels, single AB buffer, in-place bf16 h
  for (int t = 0; t < TITER; t++){
    k_agg<<<dim3(E_LINKS / 4), b256, 0, stream>>>(AB, offs, srcs, aggb);
    if (t < TITER - 1)
      k_fused<true><<<dim3(E_LINKS / 128), b256, 0, stream>>>(aggb, h_bf,
          WzrT, WxhT, WhhT, WcT, bzr, bxhv, bhhv, b_msg, AB);
    else
      k_fused<false><<<dim3(E_LINKS / 128), b256, 0, stream>>>(aggb, h_bf,
          WzrT, WxhT, WhhT, WcT, bzr, bxhv, bhhv, b_msg, AB);
  }

  // readout
  k_mlp<<<dim3(GG), b256, 0, stream>>>(h_bf, goffs, W1, b1, W2, b2, W3, b3, out);
}

// Round 14
// 933.556 us; speedup vs baseline: 2.2146x; 1.0100x over previous
//
#include <hip/hip_runtime.h>
#include <hip/hip_bf16.h>

// Problem constants (match reference)
#define E_LINKS 131072
#define M_PAIRS 1048576
#define DDIM    64
#define GG      1024
#define RUNITS  256
#define TITER   8

typedef __attribute__((ext_vector_type(8))) short bf16x8;
typedef __attribute__((ext_vector_type(4))) float f32x4;
typedef __attribute__((ext_vector_type(16))) float f32x16;

// HW bf16 convert (RNE)
__device__ inline unsigned short f2bf(float f){
  __bf16 b = (__bf16)f;
  unsigned short u;
  __builtin_memcpy(&u, &b, 2);
  return u;
}
__device__ inline float bf2f(unsigned short u){
  union { unsigned int u; float f; } v; v.u = ((unsigned int)u) << 16; return v.f;
}
__device__ inline float selu_f(float x){
  return x > 0.f ? 1.0507009873554805f * x
                 : 1.7580993408473766f * (__expf(x) - 1.f);
}
__device__ inline float sigmoid_f(float x){ return 1.f / (1.f + __expf(-x)); }
__device__ inline float tanh_f(float x){
  float xc = fminf(fmaxf(x, -15.f), 15.f);
  float e2 = __expf(2.f * xc);
  return (e2 - 1.f) / (e2 + 1.f);
}

__device__ inline bf16x8 packbf8f(float4 u0, float4 u1){
  bf16x8 r;
  r[0] = (short)f2bf(u0.x); r[1] = (short)f2bf(u0.y);
  r[2] = (short)f2bf(u0.z); r[3] = (short)f2bf(u0.w);
  r[4] = (short)f2bf(u1.x); r[5] = (short)f2bf(u1.y);
  r[6] = (short)f2bf(u1.z); r[7] = (short)f2bf(u1.w);
  return r;
}

__device__ inline f32x16 zero16(){
  f32x16 v;
  #pragma unroll
  for (int i = 0; i < 16; i++) v[i] = 0.f;
  return v;
}

// ---------------- preprocessing ----------------

// Merged: zero counts + graph offsets + weight prep. 512 blocks x 256 threads.
__global__ __launch_bounds__(256) void k_misc(const int* __restrict__ gid,
    const float* __restrict__ W_msg,
    const float* __restrict__ gk, const float* __restrict__ grk,
    const float* __restrict__ bi, const float* __restrict__ br,
    int* __restrict__ counts, int* __restrict__ goffs,
    unsigned short* __restrict__ WzrT, unsigned short* __restrict__ WxhT,
    unsigned short* __restrict__ WhhT, unsigned short* __restrict__ WcT,
    float* __restrict__ bzr, float* __restrict__ bxh, float* __restrict__ bhh){
  int i = blockIdx.x * blockDim.x + threadIdx.x;
  counts[i] = 0;
  {
    int g = gid[i];
    int gp = (i == 0) ? -1 : gid[i - 1];
    for (int x = gp + 1; x <= g; x++) goffs[x] = i;
    if (i == E_LINKS - 1){
      for (int x = g + 1; x <= GG; x++) goffs[x] = E_LINKS;
    }
  }
  if (i < 16384){
    int c = i >> 7, k = i & 127;
    float v = (k < 64) ? gk[k * 192 + c] : grk[(k - 64) * 192 + c];
    WzrT[i] = f2bf(v);
  } else if (i < 20480){
    int j = i - 16384; int c = j >> 6, k = j & 63;
    WxhT[j] = f2bf(gk[k * 192 + 128 + c]);
  } else if (i < 24576){
    int j = i - 20480; int c = j >> 6, k = j & 63;
    WhhT[j] = f2bf(grk[k * 192 + 128 + c]);
  } else if (i < 32768){
    int j = i - 24576; int c = j >> 6, k = j & 63;
    float v = (c < 64) ? W_msg[k * 64 + c] : W_msg[(64 + k) * 64 + (c - 64)];
    WcT[j] = f2bf(v);
  } else if (i < 33024){
    int j = i - 32768;
    if (j < 128) bzr[j] = bi[j] + br[j];
    else if (j < 192) bxh[j - 128] = bi[j];
    else bhh[j - 192] = br[j - 64];
  }
}

__global__ void k_hist(const int* __restrict__ second, int* __restrict__ counts){
  int i = blockIdx.x * blockDim.x + threadIdx.x;
  if (i < M_PAIRS) atomicAdd(&counts[second[i]], 1);
}

__global__ __launch_bounds__(256) void k_scan_reduce(const int* __restrict__ counts,
    int* __restrict__ partials){
  __shared__ int s[256];
  int t = threadIdx.x;
  int i = blockIdx.x * 256 + t;
  s[t] = counts[i];
  __syncthreads();
  #pragma unroll
  for (int off = 128; off > 0; off >>= 1){
    if (t < off) s[t] += s[t + off];
    __syncthreads();
  }
  if (t == 0) partials[blockIdx.x] = s[0];
}

__global__ __launch_bounds__(512) void k_scan_part(int* __restrict__ partials){
  __shared__ int s[512];
  int t = threadIdx.x;
  int v = partials[t];
  s[t] = v;
  __syncthreads();
  for (int off = 1; off < 512; off <<= 1){
    int u = (t >= off) ? s[t - off] : 0;
    __syncthreads();
    s[t] += u;
    __syncthreads();
  }
  partials[t] = s[t] - v;
}

__global__ __launch_bounds__(256) void k_scan_apply(const int* __restrict__ counts,
    const int* __restrict__ partials, int* __restrict__ offsets,
    int* __restrict__ cursor){
  __shared__ int s[256];
  int t = threadIdx.x;
  int i = blockIdx.x * 256 + t;
  int c = counts[i];
  s[t] = c;
  __syncthreads();
  for (int off = 1; off < 256; off <<= 1){
    int u = (t >= off) ? s[t - off] : 0;
    __syncthreads();
    s[t] += u;
    __syncthreads();
  }
  int run = partials[blockIdx.x] + s[t] - c;
  offsets[i] = run;
  cursor[i] = run;
  if (i == E_LINKS - 1) offsets[E_LINKS] = run + c;
}

__global__ void k_scatter(const int* __restrict__ first, const int* __restrict__ second,
    int* __restrict__ cursor, int* __restrict__ srcs){
  int i = blockIdx.x * blockDim.x + threadIdx.x;
  if (i < M_PAIRS){
    int e = second[i];
    int slot = atomicAdd(&cursor[e], 1);
    srcs[slot] = first[i];
  }
}

// ---------------- main loop kernels ----------------

// A[E,64] = h @ Wc[:, 0:64]; B[E,64] = h @ Wc[:, 64:128] + b_msg.
// Also initializes the bf16 h state (fragments already hold every element once).
__global__ __launch_bounds__(256) void k_ab0(const float* __restrict__ hf,
    const unsigned short* __restrict__ WcT, const float* __restrict__ b_msg,
    unsigned short* __restrict__ Ab, unsigned short* __restrict__ Bb,
    unsigned short* __restrict__ hb){
  int wave = threadIdx.x >> 6, lane = threadIdx.x & 63;
  int row0 = (blockIdx.x * 4 + wave) * 16;
  int lr = lane & 15, lg = lane >> 4;
  f32x4 acc[8];
  #pragma unroll
  for (int i = 0; i < 8; i++) acc[i] = (f32x4){0.f, 0.f, 0.f, 0.f};
  #pragma unroll
  for (int s = 0; s < 2; s++){
    int kb = s * 32 + lg * 8;
    const float* p = hf + (size_t)(row0 + lr) * 64 + kb;
    bf16x8 a = packbf8f(*(const float4*)p, *(const float4*)(p + 4));
    *(bf16x8*)(hb + (size_t)(row0 + lr) * 64 + kb) = a;   // h state init
    #pragma unroll
    for (int ct = 0; ct < 8; ct++){
      bf16x8 b = *(const bf16x8*)(WcT + (ct * 16 + lr) * 64 + kb);
      acc[ct] = __builtin_amdgcn_mfma_f32_16x16x32_bf16(a, b, acc[ct], 0, 0, 0);
    }
  }
  #pragma unroll
  for (int ct = 0; ct < 8; ct++){
    int col = ct * 16 + lr;
    #pragma unroll
    for (int q = 0; q < 4; q++){
      int row = row0 + lg * 4 + q;
      if (col < 64)
        Ab[(size_t)row * 64 + col] = f2bf(acc[ct][q]);
      else
        Bb[(size_t)row * 64 + (col - 64)] = f2bf(acc[ct][q] + b_msg[col - 64]);
    }
  }
}

// agg[e][:] = sum over incoming msgs: selu(A[src] + B[e])
// Gathers touch only the A buffer (16.8MB footprint; one 128B line per row).
__global__ __launch_bounds__(256) void k_agg(const unsigned short* __restrict__ Ab,
    const unsigned short* __restrict__ Bb,
    const int* __restrict__ offsets, const int* __restrict__ srcs,
    unsigned short* __restrict__ agg){
  int wave = threadIdx.x >> 6, lane = threadIdx.x & 63;
  int e = blockIdx.x * 4 + wave;
  int g = lane >> 4, d = lane & 15;

  ushort4 bq = *(const ushort4*)(Bb + (size_t)e * 64 + d * 4);
  float b0 = bf2f(bq.x), b1 = bf2f(bq.y), b2 = bf2f(bq.z), b3 = bf2f(bq.w);

  int beg = offsets[e], end = offsets[e + 1];
  float a0 = 0.f, a1 = 0.f, a2 = 0.f, a3 = 0.f;

  int i = beg + g;
  for (; i + 4 < end; i += 8){
    int s0 = srcs[i];
    int s1 = srcs[i + 4];
    ushort4 q0 = *(const ushort4*)(Ab + (size_t)s0 * 64 + d * 4);
    ushort4 q1 = *(const ushort4*)(Ab + (size_t)s1 * 64 + d * 4);
    a0 += selu_f(bf2f(q0.x) + b0);
    a1 += selu_f(bf2f(q0.y) + b1);
    a2 += selu_f(bf2f(q0.z) + b2);
    a3 += selu_f(bf2f(q0.w) + b3);
    a0 += selu_f(bf2f(q1.x) + b0);
    a1 += selu_f(bf2f(q1.y) + b1);
    a2 += selu_f(bf2f(q1.z) + b2);
    a3 += selu_f(bf2f(q1.w) + b3);
  }
  if (i < end){
    int s0 = srcs[i];
    ushort4 q0 = *(const ushort4*)(Ab + (size_t)s0 * 64 + d * 4);
    a0 += selu_f(bf2f(q0.x) + b0);
    a1 += selu_f(bf2f(q0.y) + b1);
    a2 += selu_f(bf2f(q0.z) + b2);
    a3 += selu_f(bf2f(q0.w) + b3);
  }

  a0 += __shfl_xor(a0, 16, 64); a0 += __shfl_xor(a0, 32, 64);
  a1 += __shfl_xor(a1, 16, 64); a1 += __shfl_xor(a1, 32, 64);
  a2 += __shfl_xor(a2, 16, 64); a2 += __shfl_xor(a2, 32, 64);
  a3 += __shfl_xor(a3, 16, 64); a3 += __shfl_xor(a3, 32, 64);

  if (g == 0){
    ushort4 o;
    o.x = f2bf(a0); o.y = f2bf(a1); o.z = f2bf(a2); o.w = f2bf(a3);
    *(ushort4*)(agg + (size_t)e * 64 + d * 4) = o;
  }
}

// Fused GRU (+ optional A/B production), 32 rows/wave via 32x32x16 MFMA.
// h state bf16, in place. LDS hold tile unioned with transpose tile.
template<bool WITH_AB>
__global__ __launch_bounds__(256, 4) void k_fused(const unsigned short* __restrict__ agg,
    unsigned short* h,
    const unsigned short* __restrict__ WzrT, const unsigned short* __restrict__ WxhT,
    const unsigned short* __restrict__ WhhT, const unsigned short* __restrict__ WcT,
    const float* __restrict__ bzr, const float* __restrict__ bxh,
    const float* __restrict__ bhh, const float* __restrict__ b_msg,
    unsigned short* __restrict__ Ab, unsigned short* __restrict__ Bb){
  __shared__ float hsh[4][32][68];   // 34816B; tail-reused as tsh
  int wave = threadIdx.x >> 6, lane = threadIdx.x & 63;
  int row0 = (blockIdx.x * 4 + wave) * 32;
  int lc = lane & 31, lh = lane >> 5;
  unsigned short* tsh = (unsigned short*)&hsh[wave][0][0]; // [32][64] bf16, swizzled

  // ---- A fragments over combined K=128 ([agg | h]) + fp32 hold stash ----
  bf16x8 az[8];
  const unsigned short* arow = agg + (size_t)(row0 + lc) * 64 + lh * 8;
  #pragma unroll
  for (int s = 0; s < 4; s++) az[s] = *(const bf16x8*)(arow + s * 16);
  const unsigned short* hrow = h + (size_t)(row0 + lc) * 64 + lh * 8;
  #pragma unroll
  for (int s = 0; s < 4; s++){
    bf16x8 hv = *(const bf16x8*)(hrow + s * 16);
    az[4 + s] = hv;
    float4 u0, u1;
    u0.x = bf2f((unsigned short)hv[0]); u0.y = bf2f((unsigned short)hv[1]);
    u0.z = bf2f((unsigned short)hv[2]); u0.w = bf2f((unsigned short)hv[3]);
    u1.x = bf2f((unsigned short)hv[4]); u1.y = bf2f((unsigned short)hv[5]);
    u1.z = bf2f((unsigned short)hv[6]); u1.w = bf2f((unsigned short)hv[7]);
    *(float4*)(&hsh[wave][lc][s * 16 + lh * 8]) = u0;
    *(float4*)(&hsh[wave][lc][s * 16 + lh * 8 + 4]) = u1;
  }

  // ---- r-gate GEMM (zr tiles 2,3 -> cols 64..127) ----
  f32x16 ar0 = zero16(), ar1 = zero16();
  #pragma unroll
  for (int s = 0; s < 8; s++){
    const unsigned short* wk = WzrT + lh * 8 + s * 16;
    bf16x8 b2 = *(const bf16x8*)(wk + (size_t)(64 + lc) * 128);
    bf16x8 b3 = *(const bf16x8*)(wk + (size_t)(96 + lc) * 128);
    ar0 = __builtin_amdgcn_mfma_f32_32x32x16_bf16(az[s], b2, ar0, 0, 0, 0);
    ar1 = __builtin_amdgcn_mfma_f32_32x32x16_bf16(az[s], b3, ar1, 0, 0, 0);
  }

  float cv[2][16];

  // ---- cols 0..31: xh0 (A=agg), hh0 (A=h) -> cv[0] ----
  {
    f32x16 axh = zero16(), ahh = zero16();
    #pragma unroll
    for (int s = 0; s < 4; s++){
      const unsigned short* wx = WxhT + lh * 8 + s * 16;
      axh = __builtin_amdgcn_mfma_f32_32x32x16_bf16(az[s],
          *(const bf16x8*)(wx + (size_t)lc * 64), axh, 0, 0, 0);
      const unsigned short* wh = WhhT + lh * 8 + s * 16;
      ahh = __builtin_amdgcn_mfma_f32_32x32x16_bf16(az[4 + s],
          *(const bf16x8*)(wh + (size_t)lc * 64), ahh, 0, 0, 0);
    }
    float brv = bzr[64 + lc], bx = bxh[lc], bh = bhh[lc];
    #pragma unroll
    for (int r = 0; r < 16; r++){
      float rr = sigmoid_f(ar0[r] + brv);
      cv[0][r] = tanh_f(axh[r] + bx + rr * (ahh[r] + bh));
    }
  }

  // ---- cols 32..63: xh1, hh1 -> cv[1] ----
  {
    f32x16 axh = zero16(), ahh = zero16();
    #pragma unroll
    for (int s = 0; s < 4; s++){
      const unsigned short* wx = WxhT + lh * 8 + s * 16;
      axh = __builtin_amdgcn_mfma_f32_32x32x16_bf16(az[s],
          *(const bf16x8*)(wx + (size_t)(32 + lc) * 64), axh, 0, 0, 0);
      const unsigned short* wh = WhhT + lh * 8 + s * 16;
      ahh = __builtin_amdgcn_mfma_f32_32x32x16_bf16(az[4 + s],
          *(const bf16x8*)(wh + (size_t)(32 + lc) * 64), ahh, 0, 0, 0);
    }
    float brv = bzr[64 + 32 + lc], bx = bxh[32 + lc], bh = bhh[32 + lc];
    #pragma unroll
    for (int r = 0; r < 16; r++){
      float rr = sigmoid_f(ar1[r] + brv);
      cv[1][r] = tanh_f(axh[r] + bx + rr * (ahh[r] + bh));
    }
  }

  // ---- z-gate GEMM (zr tiles 0,1 -> cols 0..63) ----
  f32x16 azt0 = zero16(), azt1 = zero16();
  #pragma unroll
  for (int s = 0; s < 8; s++){
    const unsigned short* wk = WzrT + lh * 8 + s * 16;
    bf16x8 b0 = *(const bf16x8*)(wk + (size_t)lc * 128);
    bf16x8 b1 = *(const bf16x8*)(wk + (size_t)(32 + lc) * 128);
    azt0 = __builtin_amdgcn_mfma_f32_32x32x16_bf16(az[s], b0, azt0, 0, 0, 0);
    azt1 = __builtin_amdgcn_mfma_f32_32x32x16_bf16(az[s], b1, azt1, 0, 0, 0);
  }

  // ---- phase 1: read holds from hsh, fold z -> final v (into cv) ----
  {
    float bz0 = bzr[lc], bz1 = bzr[32 + lc];
    #pragma unroll
    for (int r = 0; r < 16; r++){
      int rl = (r & 3) + 8 * (r >> 2) + 4 * lh;
      float h0 = hsh[wave][rl][lc];
      float h1 = hsh[wave][rl][32 + lc];
      float z0 = sigmoid_f(azt0[r] + bz0);
      float z1 = sigmoid_f(azt1[r] + bz1);
      cv[0][r] = z0 * h0 + (1.f - z0) * cv[0][r];
      cv[1][r] = z1 * h1 + (1.f - z1) * cv[1][r];
    }
  }

  __syncthreads();   // all hsh reads complete before tsh overwrites the space

  // ---- phase 2: write h (bf16, in place) + tsh (LDS, swizzled) ----
  {
    int j0 = lc, j1 = 32 + lc;
    #pragma unroll
    for (int r = 0; r < 16; r++){
      int rl = (r & 3) + 8 * (r >> 2) + 4 * lh;
      size_t base = (size_t)(row0 + rl) * 64;
      unsigned short v0 = f2bf(cv[0][r]);
      unsigned short v1 = f2bf(cv[1][r]);
      h[base + j0] = v0;
      h[base + j1] = v1;
      if (WITH_AB){
        tsh[rl * 64 + (((j0 >> 3) ^ (rl & 7)) << 3) + (j0 & 7)] = v0;
        tsh[rl * 64 + (((j1 >> 3) ^ (rl & 7)) << 3) + (j1 & 7)] = v1;
      }
    }
  }

  if (WITH_AB){
    // AB GEMM: M=32, N=128, K=64; A = hn from swizzled tsh
    f32x16 acc[4];
    #pragma unroll
    for (int i = 0; i < 4; i++) acc[i] = zero16();
    #pragma unroll
    for (int s = 0; s < 4; s++){
      int blk = ((s * 2 + lh) ^ (lc & 7)) << 3;
      bf16x8 a = *(const bf16x8*)(&tsh[lc * 64 + blk]);
      const unsigned short* wc = WcT + lh * 8 + s * 16;
      #pragma unroll
      for (int ct = 0; ct < 4; ct++){
        bf16x8 b = *(const bf16x8*)(wc + (size_t)(ct * 32 + lc) * 64);
        acc[ct] = __builtin_amdgcn_mfma_f32_32x32x16_bf16(a, b, acc[ct], 0, 0, 0);
      }
    }
    #pragma unroll
    for (int ct = 0; ct < 4; ct++){
      int colh = ct * 32 + lc;           // 0..127 global col
      #pragma unroll
      for (int r = 0; r < 16; r++){
        int rl = (r & 3) + 8 * (r >> 2) + 4 * lh;
        size_t row = (size_t)(row0 + rl);
        if (ct < 2)
          Ab[row * 64 + colh] = f2bf(acc[ct][r]);
        else
          Bb[row * 64 + (colh - 64)] = f2bf(acc[ct][r] + b_msg[colh - 64]);
      }
    }
  }
}

// ---------------- readout (segment sum fused into MLP) ----------------

__global__ __launch_bounds__(256) void k_mlp(const unsigned short* __restrict__ hb,
    const int* __restrict__ goffs,
    const float* __restrict__ W1, const float* __restrict__ b1,
    const float* __restrict__ W2, const float* __restrict__ b2,
    const float* __restrict__ W3, const float* __restrict__ b3,
    float* __restrict__ out){
  __shared__ float part[4][64];
  __shared__ float sg[64];
  __shared__ float sr1[256];
  __shared__ float sr2[256];
  __shared__ float wsum[4];
  int g = blockIdx.x, t = threadIdx.x;
  int wave = t >> 6, lane = t & 63;

  int beg = goffs[g], end = goffs[g + 1];
  float acc = 0.f;
  for (int e = beg + wave; e < end; e += 4) acc += bf2f(hb[(size_t)e * 64 + lane]);
  part[wave][lane] = acc;
  __syncthreads();
  if (t < 64) sg[t] = part[0][t] + part[1][t] + part[2][t] + part[3][t];
  __syncthreads();

  float a = b1[t];
  #pragma unroll
  for (int k = 0; k < 64; k++) a += sg[k] * W1[k * 256 + t];
  sr1[t] = selu_f(a);
  __syncthreads();
  float b = b2[t];
  for (int k = 0; k < 256; k++) b += sr1[k] * W2[k * 256 + t];
  sr2[t] = selu_f(b);
  __syncthreads();
  float v = sr2[t] * W3[t];
  for (int off = 32; off > 0; off >>= 1) v += __shfl_down(v, off, 64);
  if ((t & 63) == 0) wsum[t >> 6] = v;
  __syncthreads();
  if (t == 0) out[g] = wsum[0] + wsum[1] + wsum[2] + wsum[3] + b3[0];
}

// ---------------- host ----------------

static inline size_t alignup(size_t x){ return (x + 255) & ~(size_t)255; }

extern "C" void kernel_launch(void* const* d_in, const int* in_sizes, int n_in,
                              void* d_out, int out_size, void* d_ws, size_t ws_size,
                              hipStream_t stream) {
  const float* states_action = (const float*)d_in[0];
  const int*   graph_ids     = (const int*)d_in[1];
  const int*   first         = (const int*)d_in[2];
  const int*   second        = (const int*)d_in[3];
  const float* W_msg         = (const float*)d_in[5];
  const float* b_msg         = (const float*)d_in[6];
  const float* gk            = (const float*)d_in[7];
  const float* grk           = (const float*)d_in[8];
  const float* bi            = (const float*)d_in[9];
  const float* br            = (const float*)d_in[10];
  const float* W1            = (const float*)d_in[11];
  const float* b1            = (const float*)d_in[12];
  const float* W2            = (const float*)d_in[13];
  const float* b2            = (const float*)d_in[14];
  const float* W3            = (const float*)d_in[15];
  const float* b3            = (const float*)d_in[16];
  float* out = (float*)d_out;

  char* ws = (char*)d_ws;
  size_t off = 0;
  unsigned short* h_bf   = (unsigned short*)(ws + off); off += alignup((size_t)E_LINKS * 64 * 2);
  unsigned short* aggb   = (unsigned short*)(ws + off); off += alignup((size_t)E_LINKS * 64 * 2);
  unsigned short* Abuf   = (unsigned short*)(ws + off); off += alignup((size_t)E_LINKS * 64 * 2);
  unsigned short* Bbuf   = (unsigned short*)(ws + off); off += alignup((size_t)E_LINKS * 64 * 2);
  unsigned short* WzrT   = (unsigned short*)(ws + off); off += alignup(128 * 128 * 2);
  unsigned short* WxhT   = (unsigned short*)(ws + off); off += alignup(64 * 64 * 2);
  unsigned short* WhhT   = (unsigned short*)(ws + off); off += alignup(64 * 64 * 2);
  unsigned short* WcT    = (unsigned short*)(ws + off); off += alignup(128 * 64 * 2);
  float*          bzr    = (float*)(ws + off);          off += alignup(128 * 4);
  float*          bxhv   = (float*)(ws + off);          off += alignup(64 * 4);
  float*          bhhv   = (float*)(ws + off);          off += alignup(64 * 4);
  int*            counts = (int*)(ws + off);            off += alignup((size_t)E_LINKS * 4);
  int*            offs   = (int*)(ws + off);            off += alignup(((size_t)E_LINKS + 1) * 4);
  int*            cursor = (int*)(ws + off);            off += alignup((size_t)E_LINKS * 4);
  int*            srcs   = (int*)(ws + off);            off += alignup((size_t)M_PAIRS * 4);
  int*            parts  = (int*)(ws + off);            off += alignup(512 * 4);
  int*            goffs  = (int*)(ws + off);            off += alignup(((size_t)GG + 1) * 4);

  dim3 b256(256);

  // preprocessing
  k_misc<<<dim3(512), b256, 0, stream>>>(graph_ids, W_msg, gk, grk, bi, br,
      counts, goffs, WzrT, WxhT, WhhT, WcT, bzr, bxhv, bhhv);
  k_hist<<<dim3(M_PAIRS / 256), b256, 0, stream>>>(second, counts);
  k_scan_reduce<<<dim3(512), b256, 0, stream>>>(counts, parts);
  k_scan_part<<<dim3(1), dim3(512), 0, stream>>>(parts);
  k_scan_apply<<<dim3(512), b256, 0, stream>>>(counts, parts, offs, cursor);
  k_scatter<<<dim3(M_PAIRS / 256), b256, 0, stream>>>(first, second, cursor, srcs);

  // t=0: A/B precompute + bf16 h init (fused)
  k_ab0<<<dim3(E_LINKS / 64), b256, 0, stream>>>(states_action, WcT, b_msg,
      Abuf, Bbuf, h_bf);

  // message passing: split kernels, single A/B buffers, in-place bf16 h
  for (int t = 0; t < TITER; t++){
    k_agg<<<dim3(E_LINKS / 4), b256, 0, stream>>>(Abuf, Bbuf, offs, srcs, aggb);
    if (t < TITER - 1)
      k_fused<true><<<dim3(E_LINKS / 128), b256, 0, stream>>>(aggb, h_bf,
          WzrT, WxhT, WhhT, WcT, bzr, bxhv, bhhv, b_msg, Abuf, Bbuf);
    else
      k_fused<false><<<dim3(E_LINKS / 128), b256, 0, stream>>>(aggb, h_bf,
          WzrT, WxhT, WhhT, WcT, bzr, bxhv, bhhv, b_msg, Abuf, Bbuf);
  }

  // readout
  k_mlp<<<dim3(GG), b256, 0, stream>>>(h_bf, goffs, W1, b1, W2, b2, W3, b3, out);
}

// Round 15
// 912.271 us; speedup vs baseline: 2.2663x; 1.0233x over previous
//
#include <hip/hip_runtime.h>
#include <hip/hip_bf16.h>

// Problem constants (match reference)
#define E_LINKS 131072
#define M_PAIRS 1048576
#define DDIM    64
#define GG      1024
#define RUNITS  256
#define TITER   8

typedef __attribute__((ext_vector_type(8))) short bf16x8;
typedef __attribute__((ext_vector_type(4))) float f32x4;
typedef __attribute__((ext_vector_type(16))) float f32x16;

// HW bf16 convert (RNE)
__device__ inline unsigned short f2bf(float f){
  __bf16 b = (__bf16)f;
  unsigned short u;
  __builtin_memcpy(&u, &b, 2);
  return u;
}
__device__ inline float bf2f(unsigned short u){
  union { unsigned int u; float f; } v; v.u = ((unsigned int)u) << 16; return v.f;
}
__device__ inline float selu_f(float x){
  return x > 0.f ? 1.0507009873554805f * x
                 : 1.7580993408473766f * (__expf(x) - 1.f);
}
__device__ inline float sigmoid_f(float x){ return 1.f / (1.f + __expf(-x)); }
__device__ inline float tanh_f(float x){
  float xc = fminf(fmaxf(x, -15.f), 15.f);
  float e2 = __expf(2.f * xc);
  return (e2 - 1.f) / (e2 + 1.f);
}

__device__ inline bf16x8 packbf8f(float4 u0, float4 u1){
  bf16x8 r;
  r[0] = (short)f2bf(u0.x); r[1] = (short)f2bf(u0.y);
  r[2] = (short)f2bf(u0.z); r[3] = (short)f2bf(u0.w);
  r[4] = (short)f2bf(u1.x); r[5] = (short)f2bf(u1.y);
  r[6] = (short)f2bf(u1.z); r[7] = (short)f2bf(u1.w);
  return r;
}

__device__ inline f32x16 zero16(){
  f32x16 v;
  #pragma unroll
  for (int i = 0; i < 16; i++) v[i] = 0.f;
  return v;
}

// ---------------- preprocessing ----------------

// Merged: zero counts + graph offsets + weight prep. 512 blocks x 256 threads.
__global__ __launch_bounds__(256) void k_misc(const int* __restrict__ gid,
    const float* __restrict__ W_msg,
    const float* __restrict__ gk, const float* __restrict__ grk,
    const float* __restrict__ bi, const float* __restrict__ br,
    int* __restrict__ counts, int* __restrict__ goffs,
    unsigned short* __restrict__ WzrT, unsigned short* __restrict__ WxhT,
    unsigned short* __restrict__ WhhT, unsigned short* __restrict__ WcT,
    float* __restrict__ bzr, float* __restrict__ bxh, float* __restrict__ bhh){
  int i = blockIdx.x * blockDim.x + threadIdx.x;
  counts[i] = 0;
  {
    int g = gid[i];
    int gp = (i == 0) ? -1 : gid[i - 1];
    for (int x = gp + 1; x <= g; x++) goffs[x] = i;
    if (i == E_LINKS - 1){
      for (int x = g + 1; x <= GG; x++) goffs[x] = E_LINKS;
    }
  }
  if (i < 16384){
    int c = i >> 7, k = i & 127;
    float v = (k < 64) ? gk[k * 192 + c] : grk[(k - 64) * 192 + c];
    WzrT[i] = f2bf(v);
  } else if (i < 20480){
    int j = i - 16384; int c = j >> 6, k = j & 63;
    WxhT[j] = f2bf(gk[k * 192 + 128 + c]);
  } else if (i < 24576){
    int j = i - 20480; int c = j >> 6, k = j & 63;
    WhhT[j] = f2bf(grk[k * 192 + 128 + c]);
  } else if (i < 32768){
    int j = i - 24576; int c = j >> 6, k = j & 63;
    float v = (c < 64) ? W_msg[k * 64 + c] : W_msg[(64 + k) * 64 + (c - 64)];
    WcT[j] = f2bf(v);
  } else if (i < 33024){
    int j = i - 32768;
    if (j < 128) bzr[j] = bi[j] + br[j];
    else if (j < 192) bxh[j - 128] = bi[j];
    else bhh[j - 192] = br[j - 64];
  }
}

__global__ void k_hist(const int* __restrict__ second, int* __restrict__ counts){
  int i = blockIdx.x * blockDim.x + threadIdx.x;
  if (i < M_PAIRS) atomicAdd(&counts[second[i]], 1);
}

__global__ __launch_bounds__(256) void k_scan_reduce(const int* __restrict__ counts,
    int* __restrict__ partials){
  __shared__ int s[256];
  int t = threadIdx.x;
  int i = blockIdx.x * 256 + t;
  s[t] = counts[i];
  __syncthreads();
  #pragma unroll
  for (int off = 128; off > 0; off >>= 1){
    if (t < off) s[t] += s[t + off];
    __syncthreads();
  }
  if (t == 0) partials[blockIdx.x] = s[0];
}

__global__ __launch_bounds__(512) void k_scan_part(int* __restrict__ partials){
  __shared__ int s[512];
  int t = threadIdx.x;
  int v = partials[t];
  s[t] = v;
  __syncthreads();
  for (int off = 1; off < 512; off <<= 1){
    int u = (t >= off) ? s[t - off] : 0;
    __syncthreads();
    s[t] += u;
    __syncthreads();
  }
  partials[t] = s[t] - v;
}

__global__ __launch_bounds__(256) void k_scan_apply(const int* __restrict__ counts,
    const int* __restrict__ partials, int* __restrict__ offsets,
    int* __restrict__ cursor){
  __shared__ int s[256];
  int t = threadIdx.x;
  int i = blockIdx.x * 256 + t;
  int c = counts[i];
  s[t] = c;
  __syncthreads();
  for (int off = 1; off < 256; off <<= 1){
    int u = (t >= off) ? s[t - off] : 0;
    __syncthreads();
    s[t] += u;
    __syncthreads();
  }
  int run = partials[blockIdx.x] + s[t] - c;
  offsets[i] = run;
  cursor[i] = run;
  if (i == E_LINKS - 1) offsets[E_LINKS] = run + c;
}

// Windowed scatter: 8 sequential passes; pass w handles pairs whose target
// edge is in window w (16384 edges). Writes of a pass land in ~512KB of srcs
// (L2-resident) -> lines fill before write-back, killing the 16x write
// amplification of the fully-random scatter. Each block's 4KB chunk of
// `second` stays cache-resident across the 8 re-scans.
__global__ __launch_bounds__(256) void k_scatter(const int* __restrict__ first,
    const int* __restrict__ second, int* __restrict__ cursor,
    int* __restrict__ srcs){
  int base = blockIdx.x * 1024;   // 1024 pairs per block (grid 1024)
  for (int w = 0; w < 8; w++){
    #pragma unroll
    for (int k = 0; k < 4; k++){
      int i = base + k * 256 + threadIdx.x;
      int e = second[i];
      if ((e >> 14) == w){
        int slot = atomicAdd(&cursor[e], 1);
        srcs[slot] = first[i];
      }
    }
  }
}

// ---------------- main loop kernels ----------------

// A[E,64] = h @ Wc[:, 0:64]; B[E,64] = h @ Wc[:, 64:128] + b_msg.
// Also initializes the bf16 h state.
__global__ __launch_bounds__(256) void k_ab0(const float* __restrict__ hf,
    const unsigned short* __restrict__ WcT, const float* __restrict__ b_msg,
    unsigned short* __restrict__ Ab, unsigned short* __restrict__ Bb,
    unsigned short* __restrict__ hb){
  int wave = threadIdx.x >> 6, lane = threadIdx.x & 63;
  int row0 = (blockIdx.x * 4 + wave) * 16;
  int lr = lane & 15, lg = lane >> 4;
  f32x4 acc[8];
  #pragma unroll
  for (int i = 0; i < 8; i++) acc[i] = (f32x4){0.f, 0.f, 0.f, 0.f};
  #pragma unroll
  for (int s = 0; s < 2; s++){
    int kb = s * 32 + lg * 8;
    const float* p = hf + (size_t)(row0 + lr) * 64 + kb;
    bf16x8 a = packbf8f(*(const float4*)p, *(const float4*)(p + 4));
    *(bf16x8*)(hb + (size_t)(row0 + lr) * 64 + kb) = a;   // h state init
    #pragma unroll
    for (int ct = 0; ct < 8; ct++){
      bf16x8 b = *(const bf16x8*)(WcT + (ct * 16 + lr) * 64 + kb);
      acc[ct] = __builtin_amdgcn_mfma_f32_16x16x32_bf16(a, b, acc[ct], 0, 0, 0);
    }
  }
  #pragma unroll
  for (int ct = 0; ct < 8; ct++){
    int col = ct * 16 + lr;
    #pragma unroll
    for (int q = 0; q < 4; q++){
      int row = row0 + lg * 4 + q;
      if (col < 64)
        Ab[(size_t)row * 64 + col] = f2bf(acc[ct][q]);
      else
        Bb[(size_t)row * 64 + (col - 64)] = f2bf(acc[ct][q] + b_msg[col - 64]);
    }
  }
}

// agg[e][:] = sum over incoming msgs: selu(A[src] + B[e])
__global__ __launch_bounds__(256) void k_agg(const unsigned short* __restrict__ Ab,
    const unsigned short* __restrict__ Bb,
    const int* __restrict__ offsets, const int* __restrict__ srcs,
    unsigned short* __restrict__ agg){
  int wave = threadIdx.x >> 6, lane = threadIdx.x & 63;
  int e = blockIdx.x * 4 + wave;
  int g = lane >> 4, d = lane & 15;

  ushort4 bq = *(const ushort4*)(Bb + (size_t)e * 64 + d * 4);
  float b0 = bf2f(bq.x), b1 = bf2f(bq.y), b2 = bf2f(bq.z), b3 = bf2f(bq.w);

  int beg = offsets[e], end = offsets[e + 1];
  float a0 = 0.f, a1 = 0.f, a2 = 0.f, a3 = 0.f;

  int i = beg + g;
  for (; i + 4 < end; i += 8){
    int s0 = srcs[i];
    int s1 = srcs[i + 4];
    ushort4 q0 = *(const ushort4*)(Ab + (size_t)s0 * 64 + d * 4);
    ushort4 q1 = *(const ushort4*)(Ab + (size_t)s1 * 64 + d * 4);
    a0 += selu_f(bf2f(q0.x) + b0);
    a1 += selu_f(bf2f(q0.y) + b1);
    a2 += selu_f(bf2f(q0.z) + b2);
    a3 += selu_f(bf2f(q0.w) + b3);
    a0 += selu_f(bf2f(q1.x) + b0);
    a1 += selu_f(bf2f(q1.y) + b1);
    a2 += selu_f(bf2f(q1.z) + b2);
    a3 += selu_f(bf2f(q1.w) + b3);
  }
  if (i < end){
    int s0 = srcs[i];
    ushort4 q0 = *(const ushort4*)(Ab + (size_t)s0 * 64 + d * 4);
    a0 += selu_f(bf2f(q0.x) + b0);
    a1 += selu_f(bf2f(q0.y) + b1);
    a2 += selu_f(bf2f(q0.z) + b2);
    a3 += selu_f(bf2f(q0.w) + b3);
  }

  a0 += __shfl_xor(a0, 16, 64); a0 += __shfl_xor(a0, 32, 64);
  a1 += __shfl_xor(a1, 16, 64); a1 += __shfl_xor(a1, 32, 64);
  a2 += __shfl_xor(a2, 16, 64); a2 += __shfl_xor(a2, 32, 64);
  a3 += __shfl_xor(a3, 16, 64); a3 += __shfl_xor(a3, 32, 64);

  if (g == 0){
    ushort4 o;
    o.x = f2bf(a0); o.y = f2bf(a1); o.z = f2bf(a2); o.w = f2bf(a3);
    *(ushort4*)(agg + (size_t)e * 64 + d * 4) = o;
  }
}

// Fused GRU (+ optional A/B production), 32 rows/wave via 32x32x16 MFMA.
// h state bf16, in place. LDS hold tile unioned with transpose tile.
template<bool WITH_AB>
__global__ __launch_bounds__(256, 4) void k_fused(const unsigned short* __restrict__ agg,
    unsigned short* h,
    const unsigned short* __restrict__ WzrT, const unsigned short* __restrict__ WxhT,
    const unsigned short* __restrict__ WhhT, const unsigned short* __restrict__ WcT,
    const float* __restrict__ bzr, const float* __restrict__ bxh,
    const float* __restrict__ bhh, const float* __restrict__ b_msg,
    unsigned short* __restrict__ Ab, unsigned short* __restrict__ Bb){
  __shared__ float hsh[4][32][68];   // 34816B; tail-reused as tsh
  int wave = threadIdx.x >> 6, lane = threadIdx.x & 63;
  int row0 = (blockIdx.x * 4 + wave) * 32;
  int lc = lane & 31, lh = lane >> 5;
  unsigned short* tsh = (unsigned short*)&hsh[wave][0][0]; // [32][64] bf16, swizzled

  // ---- A fragments over combined K=128 ([agg | h]) + fp32 hold stash ----
  bf16x8 az[8];
  const unsigned short* arow = agg + (size_t)(row0 + lc) * 64 + lh * 8;
  #pragma unroll
  for (int s = 0; s < 4; s++) az[s] = *(const bf16x8*)(arow + s * 16);
  const unsigned short* hrow = h + (size_t)(row0 + lc) * 64 + lh * 8;
  #pragma unroll
  for (int s = 0; s < 4; s++){
    bf16x8 hv = *(const bf16x8*)(hrow + s * 16);
    az[4 + s] = hv;
    float4 u0, u1;
    u0.x = bf2f((unsigned short)hv[0]); u0.y = bf2f((unsigned short)hv[1]);
    u0.z = bf2f((unsigned short)hv[2]); u0.w = bf2f((unsigned short)hv[3]);
    u1.x = bf2f((unsigned short)hv[4]); u1.y = bf2f((unsigned short)hv[5]);
    u1.z = bf2f((unsigned short)hv[6]); u1.w = bf2f((unsigned short)hv[7]);
    *(float4*)(&hsh[wave][lc][s * 16 + lh * 8]) = u0;
    *(float4*)(&hsh[wave][lc][s * 16 + lh * 8 + 4]) = u1;
  }

  // ---- r-gate GEMM (zr tiles 2,3 -> cols 64..127) ----
  f32x16 ar0 = zero16(), ar1 = zero16();
  #pragma unroll
  for (int s = 0; s < 8; s++){
    const unsigned short* wk = WzrT + lh * 8 + s * 16;
    bf16x8 b2 = *(const bf16x8*)(wk + (size_t)(64 + lc) * 128);
    bf16x8 b3 = *(const bf16x8*)(wk + (size_t)(96 + lc) * 128);
    ar0 = __builtin_amdgcn_mfma_f32_32x32x16_bf16(az[s], b2, ar0, 0, 0, 0);
    ar1 = __builtin_amdgcn_mfma_f32_32x32x16_bf16(az[s], b3, ar1, 0, 0, 0);
  }

  float cv[2][16];

  // ---- cols 0..31: xh0 (A=agg), hh0 (A=h) -> cv[0] ----
  {
    f32x16 axh = zero16(), ahh = zero16();
    #pragma unroll
    for (int s = 0; s < 4; s++){
      const unsigned short* wx = WxhT + lh * 8 + s * 16;
      axh = __builtin_amdgcn_mfma_f32_32x32x16_bf16(az[s],
          *(const bf16x8*)(wx + (size_t)lc * 64), axh, 0, 0, 0);
      const unsigned short* wh = WhhT + lh * 8 + s * 16;
      ahh = __builtin_amdgcn_mfma_f32_32x32x16_bf16(az[4 + s],
          *(const bf16x8*)(wh + (size_t)lc * 64), ahh, 0, 0, 0);
    }
    float brv = bzr[64 + lc], bx = bxh[lc], bh = bhh[lc];
    #pragma unroll
    for (int r = 0; r < 16; r++){
      float rr = sigmoid_f(ar0[r] + brv);
      cv[0][r] = tanh_f(axh[r] + bx + rr * (ahh[r] + bh));
    }
  }

  // ---- cols 32..63: xh1, hh1 -> cv[1] ----
  {
    f32x16 axh = zero16(), ahh = zero16();
    #pragma unroll
    for (int s = 0; s < 4; s++){
      const unsigned short* wx = WxhT + lh * 8 + s * 16;
      axh = __builtin_amdgcn_mfma_f32_32x32x16_bf16(az[s],
          *(const bf16x8*)(wx + (size_t)(32 + lc) * 64), axh, 0, 0, 0);
      const unsigned short* wh = WhhT + lh * 8 + s * 16;
      ahh = __builtin_amdgcn_mfma_f32_32x32x16_bf16(az[4 + s],
          *(const bf16x8*)(wh + (size_t)(32 + lc) * 64), ahh, 0, 0, 0);
    }
    float brv = bzr[64 + 32 + lc], bx = bxh[32 + lc], bh = bhh[32 + lc];
    #pragma unroll
    for (int r = 0; r < 16; r++){
      float rr = sigmoid_f(ar1[r] + brv);
      cv[1][r] = tanh_f(axh[r] + bx + rr * (ahh[r] + bh));
    }
  }

  // ---- z-gate GEMM (zr tiles 0,1 -> cols 0..63) ----
  f32x16 azt0 = zero16(), azt1 = zero16();
  #pragma unroll
  for (int s = 0; s < 8; s++){
    const unsigned short* wk = WzrT + lh * 8 + s * 16;
    bf16x8 b0 = *(const bf16x8*)(wk + (size_t)lc * 128);
    bf16x8 b1 = *(const bf16x8*)(wk + (size_t)(32 + lc) * 128);
    azt0 = __builtin_amdgcn_mfma_f32_32x32x16_bf16(az[s], b0, azt0, 0, 0, 0);
    azt1 = __builtin_amdgcn_mfma_f32_32x32x16_bf16(az[s], b1, azt1, 0, 0, 0);
  }

  // ---- phase 1: read holds from hsh, fold z -> final v (into cv) ----
  {
    float bz0 = bzr[lc], bz1 = bzr[32 + lc];
    #pragma unroll
    for (int r = 0; r < 16; r++){
      int rl = (r & 3) + 8 * (r >> 2) + 4 * lh;
      float h0 = hsh[wave][rl][lc];
      float h1 = hsh[wave][rl][32 + lc];
      float z0 = sigmoid_f(azt0[r] + bz0);
      float z1 = sigmoid_f(azt1[r] + bz1);
      cv[0][r] = z0 * h0 + (1.f - z0) * cv[0][r];
      cv[1][r] = z1 * h1 + (1.f - z1) * cv[1][r];
    }
  }

  __syncthreads();   // all hsh reads complete before tsh overwrites the space

  // ---- phase 2: write h (bf16, in place) + tsh (LDS, swizzled) ----
  {
    int j0 = lc, j1 = 32 + lc;
    #pragma unroll
    for (int r = 0; r < 16; r++){
      int rl = (r & 3) + 8 * (r >> 2) + 4 * lh;
      size_t base = (size_t)(row0 + rl) * 64;
      unsigned short v0 = f2bf(cv[0][r]);
      unsigned short v1 = f2bf(cv[1][r]);
      h[base + j0] = v0;
      h[base + j1] = v1;
      if (WITH_AB){
        tsh[rl * 64 + (((j0 >> 3) ^ (rl & 7)) << 3) + (j0 & 7)] = v0;
        tsh[rl * 64 + (((j1 >> 3) ^ (rl & 7)) << 3) + (j1 & 7)] = v1;
      }
    }
  }

  if (WITH_AB){
    // AB GEMM: M=32, N=128, K=64; A = hn from swizzled tsh
    f32x16 acc[4];
    #pragma unroll
    for (int i = 0; i < 4; i++) acc[i] = zero16();
    #pragma unroll
    for (int s = 0; s < 4; s++){
      int blk = ((s * 2 + lh) ^ (lc & 7)) << 3;
      bf16x8 a = *(const bf16x8*)(&tsh[lc * 64 + blk]);
      const unsigned short* wc = WcT + lh * 8 + s * 16;
      #pragma unroll
      for (int ct = 0; ct < 4; ct++){
        bf16x8 b = *(const bf16x8*)(wc + (size_t)(ct * 32 + lc) * 64);
        acc[ct] = __builtin_amdgcn_mfma_f32_32x32x16_bf16(a, b, acc[ct], 0, 0, 0);
      }
    }
    #pragma unroll
    for (int ct = 0; ct < 4; ct++){
      int colh = ct * 32 + lc;           // 0..127 global col
      #pragma unroll
      for (int r = 0; r < 16; r++){
        int rl = (r & 3) + 8 * (r >> 2) + 4 * lh;
        size_t row = (size_t)(row0 + rl);
        if (ct < 2)
          Ab[row * 64 + colh] = f2bf(acc[ct][r]);
        else
          Bb[row * 64 + (colh - 64)] = f2bf(acc[ct][r] + b_msg[colh - 64]);
      }
    }
  }
}

// ---------------- readout (segment sum fused into MLP) ----------------

__global__ __launch_bounds__(256) void k_mlp(const unsigned short* __restrict__ hb,
    const int* __restrict__ goffs,
    const float* __restrict__ W1, const float* __restrict__ b1,
    const float* __restrict__ W2, const float* __restrict__ b2,
    const float* __restrict__ W3, const float* __restrict__ b3,
    float* __restrict__ out){
  __shared__ float part[4][64];
  __shared__ float sg[64];
  __shared__ float sr1[256];
  __shared__ float sr2[256];
  __shared__ float wsum[4];
  int g = blockIdx.x, t = threadIdx.x;
  int wave = t >> 6, lane = t & 63;

  int beg = goffs[g], end = goffs[g + 1];
  float acc = 0.f;
  for (int e = beg + wave; e < end; e += 4) acc += bf2f(hb[(size_t)e * 64 + lane]);
  part[wave][lane] = acc;
  __syncthreads();
  if (t < 64) sg[t] = part[0][t] + part[1][t] + part[2][t] + part[3][t];
  __syncthreads();

  float a = b1[t];
  #pragma unroll
  for (int k = 0; k < 64; k++) a += sg[k] * W1[k * 256 + t];
  sr1[t] = selu_f(a);
  __syncthreads();
  float b = b2[t];
  for (int k = 0; k < 256; k++) b += sr1[k] * W2[k * 256 + t];
  sr2[t] = selu_f(b);
  __syncthreads();
  float v = sr2[t] * W3[t];
  for (int off = 32; off > 0; off >>= 1) v += __shfl_down(v, off, 64);
  if ((t & 63) == 0) wsum[t >> 6] = v;
  __syncthreads();
  if (t == 0) out[g] = wsum[0] + wsum[1] + wsum[2] + wsum[3] + b3[0];
}

// ---------------- host ----------------

static inline size_t alignup(size_t x){ return (x + 255) & ~(size_t)255; }

extern "C" void kernel_launch(void* const* d_in, const int* in_sizes, int n_in,
                              void* d_out, int out_size, void* d_ws, size_t ws_size,
                              hipStream_t stream) {
  const float* states_action = (const float*)d_in[0];
  const int*   graph_ids     = (const int*)d_in[1];
  const int*   first         = (const int*)d_in[2];
  const int*   second        = (const int*)d_in[3];
  const float* W_msg         = (const float*)d_in[5];
  const float* b_msg         = (const float*)d_in[6];
  const float* gk            = (const float*)d_in[7];
  const float* grk           = (const float*)d_in[8];
  const float* bi            = (const float*)d_in[9];
  const float* br            = (const float*)d_in[10];
  const float* W1            = (const float*)d_in[11];
  const float* b1            = (const float*)d_in[12];
  const float* W2            = (const float*)d_in[13];
  const float* b2            = (const float*)d_in[14];
  const float* W3            = (const float*)d_in[15];
  const float* b3            = (const float*)d_in[16];
  float* out = (float*)d_out;

  char* ws = (char*)d_ws;
  size_t off = 0;
  unsigned short* h_bf   = (unsigned short*)(ws + off); off += alignup((size_t)E_LINKS * 64 * 2);
  unsigned short* aggb   = (unsigned short*)(ws + off); off += alignup((size_t)E_LINKS * 64 * 2);
  unsigned short* Abuf   = (unsigned short*)(ws + off); off += alignup((size_t)E_LINKS * 64 * 2);
  unsigned short* Bbuf   = (unsigned short*)(ws + off); off += alignup((size_t)E_LINKS * 64 * 2);
  unsigned short* WzrT   = (unsigned short*)(ws + off); off += alignup(128 * 128 * 2);
  unsigned short* WxhT   = (unsigned short*)(ws + off); off += alignup(64 * 64 * 2);
  unsigned short* WhhT   = (unsigned short*)(ws + off); off += alignup(64 * 64 * 2);
  unsigned short* WcT    = (unsigned short*)(ws + off); off += alignup(128 * 64 * 2);
  float*          bzr    = (float*)(ws + off);          off += alignup(128 * 4);
  float*          bxhv   = (float*)(ws + off);          off += alignup(64 * 4);
  float*          bhhv   = (float*)(ws + off);          off += alignup(64 * 4);
  int*            counts = (int*)(ws + off);            off += alignup((size_t)E_LINKS * 4);
  int*            offs   = (int*)(ws + off);            off += alignup(((size_t)E_LINKS + 1) * 4);
  int*            cursor = (int*)(ws + off);            off += alignup((size_t)E_LINKS * 4);
  int*            srcs   = (int*)(ws + off);            off += alignup((size_t)M_PAIRS * 4);
  int*            parts  = (int*)(ws + off);            off += alignup(512 * 4);
  int*            goffs  = (int*)(ws + off);            off += alignup(((size_t)GG + 1) * 4);

  dim3 b256(256);

  // preprocessing
  k_misc<<<dim3(512), b256, 0, stream>>>(graph_ids, W_msg, gk, grk, bi, br,
      counts, goffs, WzrT, WxhT, WhhT, WcT, bzr, bxhv, bhhv);
  k_hist<<<dim3(M_PAIRS / 256), b256, 0, stream>>>(second, counts);
  k_scan_reduce<<<dim3(512), b256, 0, stream>>>(counts, parts);
  k_scan_part<<<dim3(1), dim3(512), 0, stream>>>(parts);
  k_scan_apply<<<dim3(512), b256, 0, stream>>>(counts, parts, offs, cursor);
  k_scatter<<<dim3(M_PAIRS / 1024), b256, 0, stream>>>(first, second, cursor, srcs);

  // t=0: A/B precompute + bf16 h init (fused)
  k_ab0<<<dim3(E_LINKS / 64), b256, 0, stream>>>(states_action, WcT, b_msg,
      Abuf, Bbuf, h_bf);

  // message passing: split kernels, single A/B buffers, in-place bf16 h
  for (int t = 0; t < TITER; t++){
    k_agg<<<dim3(E_LINKS / 4), b256, 0, stream>>>(Abuf, Bbuf, offs, srcs, aggb);
    if (t < TITER - 1)
      k_fused<true><<<dim3(E_LINKS / 128), b256, 0, stream>>>(aggb, h_bf,
          WzrT, WxhT, WhhT, WcT, bzr, bxhv, bhhv, b_msg, Abuf, Bbuf);
    else
      k_fused<false><<<dim3(E_LINKS / 128), b256, 0, stream>>>(aggb, h_bf,
          WzrT, WxhT, WhhT, WcT, bzr, bxhv, bhhv, b_msg, Abuf, Bbuf);
  }

  // readout
  k_mlp<<<dim3(GG), b256, 0, stream>>>(h_bf, goffs, W1, b1, W2, b2, W3, b3, out);
}